// Round 4
// baseline (380.753 us; speedup 1.0000x reference)
//
#include <hip/hip_runtime.h>

typedef __attribute__((ext_vector_type(8))) short short8;
typedef __attribute__((ext_vector_type(4))) short s16x4;
typedef __attribute__((ext_vector_type(4))) float f32x4;

static __device__ __forceinline__ short f2bf(float x) {
  union { float f; unsigned u; } v; v.f = x;
  unsigned r = (v.u + 0x7fffu + ((v.u >> 16) & 1u)) >> 16;
  return (short)r;
}

// dst = bf16(src * scale), 8 elems/thread
__global__ __launch_bounds__(256) void convert_f32_bf16(const float* __restrict__ src,
                                                        short* __restrict__ dst, int n8,
                                                        float scale) {
  int i = blockIdx.x * 256 + threadIdx.x;
  if (i >= n8) return;
  const f32x4* s = (const f32x4*)(src + (long)i * 8);
  f32x4 a = s[0], b = s[1];
  short8 o;
  o[0] = f2bf(a[0] * scale); o[1] = f2bf(a[1] * scale);
  o[2] = f2bf(a[2] * scale); o[3] = f2bf(a[3] * scale);
  o[4] = f2bf(b[0] * scale); o[5] = f2bf(b[1] * scale);
  o[6] = f2bf(b[2] * scale); o[7] = f2bf(b[3] * scale);
  *(short8*)(dst + (long)i * 8) = o;
}

// bqs = 0.125 * bq (1024 elems)
__global__ __launch_bounds__(256) void scale_bias(const float* __restrict__ src,
                                                  float* __restrict__ dst) {
  int i = blockIdx.x * 256 + threadIdx.x;
  dst[i] = src[i] * 0.125f;
}

// Wpb[o][g*64+d] = Wp[o][d*16+g]  (column permutation folded into bf16 convert)
__global__ __launch_bounds__(256) void convert_permute_wp(const float* __restrict__ src,
                                                          short* __restrict__ dst) {
  __shared__ float row[1024];
  const long o = blockIdx.x;
  *(f32x4*)&row[threadIdx.x * 4] = *(const f32x4*)(src + o * 1024 + threadIdx.x * 4);
  __syncthreads();
  const int f0 = threadIdx.x * 4;
  s16x4 t;
#pragma unroll
  for (int j = 0; j < 4; ++j) {
    int f = f0 + j;
    t[j] = f2bf(row[((f & 63) << 4) + (f >> 6)]);
  }
  *(s16x4*)(dst + o * 1024 + f0) = t;
}

// C[M,N] = scale * A[M,K] @ B[N,K]^T + bias + resid.
// A: f32 (AF32, converted during staging) or bf16. B: bf16 [N][K].
// OMODE 0: C[row*ldc + col]; OMODE 1: vt store C[(row>>10)<<20 | col<<10 | row&1023].
template <int OMODE, bool AF32, typename OutT>
__global__ __launch_bounds__(256) void gemm_mfma(
    const void* __restrict__ Abase, int lda,
    const short* __restrict__ Bbase, int ldb,
    OutT* __restrict__ Cbase, int ldc,
    const float* __restrict__ bias,
    const float* __restrict__ resid, int ldres,
    float scale, int K, int nbn) {
  constexpr int LDK = 72;
  __shared__ short As[64 * LDK];
  __shared__ short Bs[64 * LDK];

  const int nwg = gridDim.x;
  const int cpx = nwg >> 3;
  int bid = blockIdx.x;
  bid = (bid & 7) * cpx + (bid >> 3);
  const int bn = (bid % nbn) * 64, bm = (bid / nbn) * 64;

  const int tid = threadIdx.x, lane = tid & 63, wave = tid >> 6;
  const int fr = lane & 15, khi = lane >> 4;
  const int srow = tid >> 3, scol = (tid & 7) * 8;

  const short* A16 = AF32 ? nullptr : (const short*)Abase;
  const float* A32 = AF32 ? (const float*)Abase : nullptr;

  f32x4 acc[4];
#pragma unroll
  for (int n = 0; n < 4; ++n) acc[n] = (f32x4){0.f, 0.f, 0.f, 0.f};

  for (int k0 = 0; k0 < K; k0 += 64) {
#pragma unroll
    for (int it = 0; it < 2; ++it) {
      int r = it * 32 + srow;
      if (!AF32) {
        *(short8*)&As[r * LDK + scol] =
            *(const short8*)(A16 + (long)(bm + r) * lda + k0 + scol);
      } else {
        const float* p = A32 + (long)(bm + r) * lda + k0 + scol;
        f32x4 x = *(const f32x4*)p, y = *(const f32x4*)(p + 4);
        short8 o;
        o[0] = f2bf(x[0]); o[1] = f2bf(x[1]); o[2] = f2bf(x[2]); o[3] = f2bf(x[3]);
        o[4] = f2bf(y[0]); o[5] = f2bf(y[1]); o[6] = f2bf(y[2]); o[7] = f2bf(y[3]);
        *(short8*)&As[r * LDK + scol] = o;
      }
      *(short8*)&Bs[r * LDK + scol] =
          *(const short8*)(Bbase + (long)(bn + r) * ldb + k0 + scol);
    }
    __syncthreads();
#pragma unroll
    for (int ks = 0; ks < 64; ks += 32) {
      short8 af = *(const short8*)&As[(wave * 16 + fr) * LDK + ks + khi * 8];
#pragma unroll
      for (int n = 0; n < 4; ++n) {
        short8 bf = *(const short8*)&Bs[(n * 16 + fr) * LDK + ks + khi * 8];
        acc[n] = __builtin_amdgcn_mfma_f32_16x16x32_bf16(af, bf, acc[n], 0, 0, 0);
      }
    }
    __syncthreads();
  }

  const int col0 = lane & 15, row0 = (lane >> 4) * 4;
#pragma unroll
  for (int n = 0; n < 4; ++n) {
    int gcol = bn + n * 16 + col0;
    float bi = bias ? bias[gcol] : 0.f;
#pragma unroll
    for (int i = 0; i < 4; ++i) {
      int grow = bm + wave * 16 + row0 + i;
      float v = acc[n][i] * scale + bi;
      if (resid) v += resid[(long)grow * ldres + gcol];
      long addr;
      if (OMODE == 0)
        addr = (long)grow * ldc + gcol;
      else
        addr = ((long)(grow >> 10) << 20) + ((long)gcol << 10) + (grow & 1023);
      if constexpr (sizeof(OutT) == 2)
        Cbase[addr] = (OutT)f2bf(v);
      else
        Cbase[addr] = v;
    }
  }
}

// Fused attention v4: block = 512 thr (8 waves) per (z, 64 q-rows).
// Wave w: q-subtile qs = w>>1 (16 rows), key-half = w&1 (512 keys).
// Sum-only softmax (logits ~ N(0,1): max<<88, exact in f32); qb pre-scaled by 1/8.
__global__ __launch_bounds__(512, 6) void fused_attn(
    const short* __restrict__ qb,   // [4][1024][1024] bf16, feat = g*64+d (x0.125)
    const short* __restrict__ kb,   // [4][1024][1024] bf16, feat = g*64+d
    const short* __restrict__ vt,   // [4][1024][1024] bf16, vt[b][d*16+g][t]
    float* __restrict__ scores,     // [64][1024][1024] f32
    short* __restrict__ at) {       // [4][1024][1024] bf16, feat = g*64+d
  constexpr int LP = 136;
  __shared__ short Ps[128 * LP];    // 34816 B
  __shared__ float Sx[8 * 16];
  float* Pc = (float*)Ps;           // overlay after PV: [4 pairs][16][65] f32

  int bid = blockIdx.x;
  bid = (bid & 7) * 128 + (bid >> 3);     // 8 z's per XCD
  const int z = bid >> 4, b = z >> 4, g = z & 15;
  const int q0 = (bid & 15) * 64;

  const int tid = threadIdx.x, lane = tid & 63, w = tid >> 6;
  const int qs = w >> 1, half = w & 1;
  const int fr = lane & 15, khi = lane >> 4;
  const long bqk = (long)b << 20;
  const int k0 = half * 512;

  const short* qrow = qb + bqk + (long)(q0 + qs * 16 + fr) * 1024 + g * 64 + khi * 8;
  const short8 aq0 = *(const short8*)qrow;
  const short8 aq1 = *(const short8*)(qrow + 32);
  const short* kg = kb + bqk + g * 64 + khi * 8;

  // ---- pass 1: per-lane exp-sums (no per-tile shuffles) ----
  float s4[4] = {0.f, 0.f, 0.f, 0.f};
  for (int t0 = k0; t0 < k0 + 512; t0 += 128) {
#pragma unroll
    for (int c = 0; c < 2; ++c) {
      f32x4 sacc[4];
#pragma unroll
      for (int nf = 0; nf < 4; ++nf) sacc[nf] = (f32x4){0.f, 0.f, 0.f, 0.f};
#pragma unroll
      for (int nf = 0; nf < 4; ++nf) {
        const short* kr = kg + (long)(t0 + c * 64 + nf * 16 + fr) * 1024;
        short8 b0 = *(const short8*)kr;
        short8 b1 = *(const short8*)(kr + 32);
        sacc[nf] = __builtin_amdgcn_mfma_f32_16x16x32_bf16(aq0, b0, sacc[nf], 0, 0, 0);
        sacc[nf] = __builtin_amdgcn_mfma_f32_16x16x32_bf16(aq1, b1, sacc[nf], 0, 0, 0);
      }
#pragma unroll
      for (int nf = 0; nf < 4; ++nf)
#pragma unroll
        for (int i = 0; i < 4; ++i) s4[i] += __expf(sacc[nf][i]);
    }
  }
#pragma unroll
  for (int i = 0; i < 4; ++i) {
    s4[i] += __shfl_xor(s4[i], 1);
    s4[i] += __shfl_xor(s4[i], 2);
    s4[i] += __shfl_xor(s4[i], 4);
    s4[i] += __shfl_xor(s4[i], 8);
  }
  if (fr == 0) {
#pragma unroll
    for (int i = 0; i < 4; ++i) Sx[w * 16 + khi * 4 + i] = s4[i];
  }
  __syncthreads();
  float inv4[4];
#pragma unroll
  for (int i = 0; i < 4; ++i)
    inv4[i] = 1.f / (s4[i] + Sx[(w ^ 1) * 16 + khi * 4 + i]);

  // ---- pass 2: recompute, write scores, accumulate PV ----
  f32x4 pacc[4];
#pragma unroll
  for (int nv = 0; nv < 4; ++nv) pacc[nv] = (f32x4){0.f, 0.f, 0.f, 0.f};

  for (int t0 = k0; t0 < k0 + 512; t0 += 128) {
#pragma unroll
    for (int c = 0; c < 2; ++c) {
      f32x4 sacc[4];
#pragma unroll
      for (int nf = 0; nf < 4; ++nf) sacc[nf] = (f32x4){0.f, 0.f, 0.f, 0.f};
#pragma unroll
      for (int nf = 0; nf < 4; ++nf) {
        const short* kr = kg + (long)(t0 + c * 64 + nf * 16 + fr) * 1024;
        short8 b0 = *(const short8*)kr;
        short8 b1 = *(const short8*)(kr + 32);
        sacc[nf] = __builtin_amdgcn_mfma_f32_16x16x32_bf16(aq0, b0, sacc[nf], 0, 0, 0);
        sacc[nf] = __builtin_amdgcn_mfma_f32_16x16x32_bf16(aq1, b1, sacc[nf], 0, 0, 0);
      }
#pragma unroll
      for (int nf = 0; nf < 4; ++nf) {
#pragma unroll
        for (int i = 0; i < 4; ++i) {
          float p = __expf(sacc[nf][i]) * inv4[i];
          scores[((long)z << 20) + ((long)(q0 + qs * 16 + khi * 4 + i) << 10) + t0 +
                 c * 64 + nf * 16 + fr] = p;
          Ps[(w * 16 + khi * 4 + i) * LP + c * 64 + nf * 16 + fr] = f2bf(p);
        }
      }
    }
#pragma unroll
    for (int ks = 0; ks < 128; ks += 32) {
      short8 ap = *(const short8*)&Ps[(w * 16 + fr) * LP + ks + khi * 8];
#pragma unroll
      for (int nv = 0; nv < 4; ++nv) {
        const short* vr = vt + bqk + ((long)((nv * 16 + fr) * 16 + g) << 10) + t0 +
                          ks + khi * 8;
        pacc[nv] = __builtin_amdgcn_mfma_f32_16x16x32_bf16(ap, *(const short8*)vr,
                                                           pacc[nv], 0, 0, 0);
      }
    }
  }

  // ---- pair-combine pacc, write at[b][s][g*64+d] ----
  __syncthreads();
  if (half) {
#pragma unroll
    for (int nv = 0; nv < 4; ++nv)
#pragma unroll
      for (int i = 0; i < 4; ++i)
        Pc[(qs * 16 + khi * 4 + i) * 65 + nv * 16 + fr] = pacc[nv][i];
  }
  __syncthreads();
  if (!half) {
#pragma unroll
    for (int nv = 0; nv < 4; ++nv) {
#pragma unroll
      for (int i = 0; i < 4; ++i) {
        float v = pacc[nv][i] + Pc[(qs * 16 + khi * 4 + i) * 65 + nv * 16 + fr];
        at[bqk + ((long)(q0 + qs * 16 + khi * 4 + i) << 10) + g * 64 + nv * 16 + fr] =
            f2bf(v);
      }
    }
  }
}

// one wave per 1024-elem row
__global__ __launch_bounds__(256) void layernorm_rows(const float* __restrict__ X,
                                                      const float* __restrict__ gamma,
                                                      const float* __restrict__ beta,
                                                      float* __restrict__ O) {
  const int row = blockIdx.x * 4 + (threadIdx.x >> 6);
  const int lane = threadIdx.x & 63;
  const float* x = X + (long)row * 1024 + lane * 4;
  f32x4 v[4];
  float s = 0.f, sq = 0.f;
#pragma unroll
  for (int j = 0; j < 4; ++j) {
    v[j] = *(const f32x4*)(x + j * 256);
#pragma unroll
    for (int e = 0; e < 4; ++e) {
      s += v[j][e];
      sq += v[j][e] * v[j][e];
    }
  }
#pragma unroll
  for (int off = 32; off; off >>= 1) {
    s += __shfl_xor(s, off);
    sq += __shfl_xor(sq, off);
  }
  const float mu = s * (1.f / 1024.f);
  const float var = sq * (1.f / 1024.f) - mu * mu;
  const float rstd = rsqrtf(var + 1e-5f);
  float* o = O + (long)row * 1024 + lane * 4;
#pragma unroll
  for (int j = 0; j < 4; ++j) {
    f32x4 g = *(const f32x4*)(gamma + lane * 4 + j * 256);
    f32x4 be = *(const f32x4*)(beta + lane * 4 + j * 256);
    f32x4 r;
#pragma unroll
    for (int e = 0; e < 4; ++e) r[e] = (v[j][e] - mu) * rstd * g[e] + be[e];
    *(f32x4*)(o + j * 256) = r;
  }
}

extern "C" void kernel_launch(void* const* d_in, const int* in_sizes, int n_in,
                              void* d_out, int out_size, void* d_ws, size_t ws_size,
                              hipStream_t stream) {
  const float* Q = (const float*)d_in[0];
  const float* KV = (const float*)d_in[1];
  const float* Wq = (const float*)d_in[2];
  const float* bq = (const float*)d_in[3];
  const float* Wk = (const float*)d_in[4];
  const float* bk = (const float*)d_in[5];
  const float* Wv = (const float*)d_in[6];
  const float* bv = (const float*)d_in[7];
  const float* Wp = (const float*)d_in[8];
  const float* bp = (const float*)d_in[9];
  const float* gamma = (const float*)d_in[10];
  const float* beta = (const float*)d_in[11];

  float* out = (float*)d_out;                       // [4M] f32
  float* scores = out + (long)4 * 1024 * 1024;      // [64M] f32

  char* ws = (char*)d_ws;
  short* Wqb = (short*)(ws);                        // 2MB each
  short* Wkb = (short*)(ws + (2L << 20));
  short* Wvb = (short*)(ws + (4L << 20));
  short* Wpb = (short*)(ws + (6L << 20));           // permuted columns
  short* qb  = (short*)(ws + (8L << 20));           // 8MB (pre-scaled by 1/8)
  short* kb  = (short*)(ws + (16L << 20));          // 8MB
  short* vt  = (short*)(ws + (24L << 20));          // 8MB
  short* at  = (short*)(ws + (32L << 20));          // 8MB, feat = g*64+d
  float* pre = (float*)(ws + (40L << 20));          // 16MB
  float* bqs = (float*)(ws + (56L << 20));          // 4KB -> peak ~56MB
  (void)ws_size; (void)in_sizes; (void)n_in; (void)out_size;

  // 1) weight conversions; fold the 1/8 attention scale into Wq and bq
  convert_f32_bf16<<<512, 256, 0, stream>>>(Wq, Wqb, 131072, 0.125f);
  convert_f32_bf16<<<512, 256, 0, stream>>>(Wk, Wkb, 131072, 1.f);
  convert_f32_bf16<<<512, 256, 0, stream>>>(Wv, Wvb, 131072, 1.f);
  convert_permute_wp<<<1024, 256, 0, stream>>>(Wp, Wpb);
  scale_bias<<<4, 256, 0, stream>>>(bq, bqs);

  // 2) projections (A read as f32, converted in staging)
  gemm_mfma<0, true, short><<<1024, 256, 0, stream>>>(
      Q, 1024, Wqb, 1024, qb, 1024, bqs, nullptr, 0, 1.f, 1024, 16);
  gemm_mfma<0, true, short><<<1024, 256, 0, stream>>>(
      KV, 1024, Wkb, 1024, kb, 1024, bk, nullptr, 0, 1.f, 1024, 16);
  gemm_mfma<1, true, short><<<1024, 256, 0, stream>>>(
      KV, 1024, Wvb, 1024, vt, 1024, bv, nullptr, 0, 1.f, 1024, 16);

  // 3) fused attention: scores (d_out) + at
  fused_attn<<<1024, 512, 0, stream>>>(qb, kb, vt, scores, at);

  // 4) pre = at@Wpb^T + bp + Q  (both in g*64+d feature order)
  gemm_mfma<0, false, float><<<1024, 256, 0, stream>>>(
      at, 1024, Wpb, 1024, pre, 1024, bp, Q, 1024, 1.f, 1024, 16);

  // 5) LayerNorm -> out
  layernorm_rows<<<1024, 256, 0, stream>>>(pre, gamma, beta, out);
}

// Round 5
// 258.287 us; speedup vs baseline: 1.4741x; 1.4741x over previous
//
#include <hip/hip_runtime.h>

typedef __attribute__((ext_vector_type(8))) short short8;
typedef __attribute__((ext_vector_type(4))) short s16x4;
typedef __attribute__((ext_vector_type(4))) float f32x4;

static __device__ __forceinline__ short f2bf(float x) {
  union { float f; unsigned u; } v; v.f = x;
  unsigned r = (v.u + 0x7fffu + ((v.u >> 16) & 1u)) >> 16;
  return (short)r;
}
static __device__ __forceinline__ float bf2f(short x) {
  union { unsigned u; float f; } v; v.u = ((unsigned)(unsigned short)x) << 16;
  return v.f;
}

// dst = bf16(src * scale), 8 elems/thread
__global__ __launch_bounds__(256) void convert_f32_bf16(const float* __restrict__ src,
                                                        short* __restrict__ dst, int n8,
                                                        float scale) {
  int i = blockIdx.x * 256 + threadIdx.x;
  if (i >= n8) return;
  const f32x4* s = (const f32x4*)(src + (long)i * 8);
  f32x4 a = s[0], b = s[1];
  short8 o;
  o[0] = f2bf(a[0] * scale); o[1] = f2bf(a[1] * scale);
  o[2] = f2bf(a[2] * scale); o[3] = f2bf(a[3] * scale);
  o[4] = f2bf(b[0] * scale); o[5] = f2bf(b[1] * scale);
  o[6] = f2bf(b[2] * scale); o[7] = f2bf(b[3] * scale);
  *(short8*)(dst + (long)i * 8) = o;
}

__global__ __launch_bounds__(256) void scale_bias(const float* __restrict__ src,
                                                  float* __restrict__ dst) {
  int i = blockIdx.x * 256 + threadIdx.x;
  dst[i] = src[i] * 0.125f;
}

// Wpb[o][g*64+d] = Wp[o][d*16+g]
__global__ __launch_bounds__(256) void convert_permute_wp(const float* __restrict__ src,
                                                          short* __restrict__ dst) {
  __shared__ float row[1024];
  const long o = blockIdx.x;
  *(f32x4*)&row[threadIdx.x * 4] = *(const f32x4*)(src + o * 1024 + threadIdx.x * 4);
  __syncthreads();
  const int f0 = threadIdx.x * 4;
  s16x4 t;
#pragma unroll
  for (int j = 0; j < 4; ++j) {
    int f = f0 + j;
    t[j] = f2bf(row[((f & 63) << 4) + (f >> 6)]);
  }
  *(s16x4*)(dst + o * 1024 + f0) = t;
}

// C[M,N] = scale * A[M,K] @ B[N,K]^T + bias + resid.
template <int OMODE, bool AF32, typename OutT>
__global__ __launch_bounds__(256) void gemm_mfma(
    const void* __restrict__ Abase, int lda,
    const short* __restrict__ Bbase, int ldb,
    OutT* __restrict__ Cbase, int ldc,
    const float* __restrict__ bias,
    const float* __restrict__ resid, int ldres,
    float scale, int K, int nbn) {
  constexpr int LDK = 72;
  __shared__ short As[64 * LDK];
  __shared__ short Bs[64 * LDK];

  const int nwg = gridDim.x;
  const int cpx = nwg >> 3;
  int bid = blockIdx.x;
  bid = (bid & 7) * cpx + (bid >> 3);
  const int bn = (bid % nbn) * 64, bm = (bid / nbn) * 64;

  const int tid = threadIdx.x, lane = tid & 63, wave = tid >> 6;
  const int fr = lane & 15, khi = lane >> 4;
  const int srow = tid >> 3, scol = (tid & 7) * 8;

  const short* A16 = AF32 ? nullptr : (const short*)Abase;
  const float* A32 = AF32 ? (const float*)Abase : nullptr;

  f32x4 acc[4];
#pragma unroll
  for (int n = 0; n < 4; ++n) acc[n] = (f32x4){0.f, 0.f, 0.f, 0.f};

  for (int k0 = 0; k0 < K; k0 += 64) {
#pragma unroll
    for (int it = 0; it < 2; ++it) {
      int r = it * 32 + srow;
      if (!AF32) {
        *(short8*)&As[r * LDK + scol] =
            *(const short8*)(A16 + (long)(bm + r) * lda + k0 + scol);
      } else {
        const float* p = A32 + (long)(bm + r) * lda + k0 + scol;
        f32x4 x = *(const f32x4*)p, y = *(const f32x4*)(p + 4);
        short8 o;
        o[0] = f2bf(x[0]); o[1] = f2bf(x[1]); o[2] = f2bf(x[2]); o[3] = f2bf(x[3]);
        o[4] = f2bf(y[0]); o[5] = f2bf(y[1]); o[6] = f2bf(y[2]); o[7] = f2bf(y[3]);
        *(short8*)&As[r * LDK + scol] = o;
      }
      *(short8*)&Bs[r * LDK + scol] =
          *(const short8*)(Bbase + (long)(bn + r) * ldb + k0 + scol);
    }
    __syncthreads();
#pragma unroll
    for (int ks = 0; ks < 64; ks += 32) {
      short8 af = *(const short8*)&As[(wave * 16 + fr) * LDK + ks + khi * 8];
#pragma unroll
      for (int n = 0; n < 4; ++n) {
        short8 bf = *(const short8*)&Bs[(n * 16 + fr) * LDK + ks + khi * 8];
        acc[n] = __builtin_amdgcn_mfma_f32_16x16x32_bf16(af, bf, acc[n], 0, 0, 0);
      }
    }
    __syncthreads();
  }

  const int col0 = lane & 15, row0 = (lane >> 4) * 4;
#pragma unroll
  for (int n = 0; n < 4; ++n) {
    int gcol = bn + n * 16 + col0;
    float bi = bias ? bias[gcol] : 0.f;
#pragma unroll
    for (int i = 0; i < 4; ++i) {
      int grow = bm + wave * 16 + row0 + i;
      float v = acc[n][i] * scale + bi;
      if (resid) v += resid[(long)grow * ldres + gcol];
      long addr;
      if (OMODE == 0)
        addr = (long)grow * ldc + gcol;
      else
        addr = ((long)(grow >> 10) << 20) + ((long)gcol << 10) + (grow & 1023);
      if constexpr (sizeof(OutT) == 2)
        Cbase[addr] = (OutT)f2bf(v);
      else
        Cbase[addr] = v;
    }
  }
}

// Fused attention v5: block = 512 thr (8 waves) per (z, 128 q-rows); each wave owns
// 16 q-rows x all 1024 keys. K/V staged in LDS (coalesced 128B lines); sum-only
// softmax; scores written coalesced via the bf16 Ps tile.
__global__ __launch_bounds__(512, 4) void fused_attn(
    const short* __restrict__ qb,   // [4][1024][1024] bf16, feat = g*64+d (x1/8)
    const short* __restrict__ kb,   // [4][1024][1024] bf16, feat = g*64+d
    const short* __restrict__ vt,   // [4][1024][1024] bf16, vt[b][d*16+g][t]
    float* __restrict__ scores,     // [64][1024][1024] f32
    short* __restrict__ at) {       // [4][1024][1024] bf16, feat = g*64+d
  constexpr int LK = 80;            // Ks stride (shorts): 160B -> 4-way max
  constexpr int LV = 144;           // Vs/Ps stride: 288B -> 4-way max
  __shared__ short Ks[128 * LK];    // 20.0 KB
  __shared__ short Vs[64 * LV];     // 18.0 KB
  __shared__ short Ps[128 * LV];    // 36.0 KB  (wave-private 16-row slabs)

  int bid = blockIdx.x;
  bid = (bid & 7) * 64 + (bid >> 3);      // XCD-contiguous: 8 z's per XCD
  const int z = bid >> 3, b = z >> 4, g = z & 15;
  const int q0 = (bid & 7) * 128;

  const int tid = threadIdx.x, lane = tid & 63, w = tid >> 6;
  const int fr = lane & 15, khi = lane >> 4;
  const long bqk = (long)b << 20;
  const int qr = q0 + w * 16;             // wave's first q row

  const short* qrow = qb + bqk + (long)(qr + fr) * 1024 + g * 64 + khi * 8;
  const short8 aq0 = *(const short8*)qrow;
  const short8 aq1 = *(const short8*)(qrow + 32);

  // staging indices: K rows are 128B (8 thr/row), V rows are 256B (16 thr/row)
  const int ksr = tid >> 3, ksc = (tid & 7) * 8;
  const int vsr = tid >> 4, vsc = (tid & 15) * 8;
  const short* kgp = kb + bqk + g * 64;

  // ---- pass 1: exp-sums ----
  float s4[4] = {0.f, 0.f, 0.f, 0.f};
  for (int t0 = 0; t0 < 1024; t0 += 128) {
    *(short8*)&Ks[ksr * LK + ksc] =
        *(const short8*)(kgp + (long)(t0 + ksr) * 1024 + ksc);
    *(short8*)&Ks[(64 + ksr) * LK + ksc] =
        *(const short8*)(kgp + (long)(t0 + 64 + ksr) * 1024 + ksc);
    __syncthreads();
    f32x4 sacc[8];
#pragma unroll
    for (int nf = 0; nf < 8; ++nf) sacc[nf] = (f32x4){0.f, 0.f, 0.f, 0.f};
#pragma unroll
    for (int nf = 0; nf < 8; ++nf) {
      short8 b0 = *(const short8*)&Ks[(nf * 16 + fr) * LK + khi * 8];
      short8 b1 = *(const short8*)&Ks[(nf * 16 + fr) * LK + 32 + khi * 8];
      sacc[nf] = __builtin_amdgcn_mfma_f32_16x16x32_bf16(aq0, b0, sacc[nf], 0, 0, 0);
      sacc[nf] = __builtin_amdgcn_mfma_f32_16x16x32_bf16(aq1, b1, sacc[nf], 0, 0, 0);
    }
#pragma unroll
    for (int nf = 0; nf < 8; ++nf)
#pragma unroll
      for (int i = 0; i < 4; ++i) s4[i] += __expf(sacc[nf][i]);
    __syncthreads();
  }
#pragma unroll
  for (int i = 0; i < 4; ++i) {
    s4[i] += __shfl_xor(s4[i], 1);
    s4[i] += __shfl_xor(s4[i], 2);
    s4[i] += __shfl_xor(s4[i], 4);
    s4[i] += __shfl_xor(s4[i], 8);
  }
  float inv4[4];
#pragma unroll
  for (int i = 0; i < 4; ++i) inv4[i] = 1.f / s4[i];

  // ---- pass 2: recompute, P -> Ps, PV, coalesced score write ----
  f32x4 pacc[4];
#pragma unroll
  for (int nv = 0; nv < 4; ++nv) pacc[nv] = (f32x4){0.f, 0.f, 0.f, 0.f};

  for (int t0 = 0; t0 < 1024; t0 += 128) {
    *(short8*)&Ks[ksr * LK + ksc] =
        *(const short8*)(kgp + (long)(t0 + ksr) * 1024 + ksc);
    *(short8*)&Ks[(64 + ksr) * LK + ksc] =
        *(const short8*)(kgp + (long)(t0 + 64 + ksr) * 1024 + ksc);
#pragma unroll
    for (int it = 0; it < 2; ++it) {
      int d = it * 32 + vsr;
      *(short8*)&Vs[d * LV + vsc] =
          *(const short8*)(vt + bqk + ((long)(d * 16 + g) << 10) + t0 + vsc);
    }
    __syncthreads();
    f32x4 sacc[8];
#pragma unroll
    for (int nf = 0; nf < 8; ++nf) sacc[nf] = (f32x4){0.f, 0.f, 0.f, 0.f};
#pragma unroll
    for (int nf = 0; nf < 8; ++nf) {
      short8 b0 = *(const short8*)&Ks[(nf * 16 + fr) * LK + khi * 8];
      short8 b1 = *(const short8*)&Ks[(nf * 16 + fr) * LK + 32 + khi * 8];
      sacc[nf] = __builtin_amdgcn_mfma_f32_16x16x32_bf16(aq0, b0, sacc[nf], 0, 0, 0);
      sacc[nf] = __builtin_amdgcn_mfma_f32_16x16x32_bf16(aq1, b1, sacc[nf], 0, 0, 0);
    }
#pragma unroll
    for (int nf = 0; nf < 8; ++nf)
#pragma unroll
      for (int i = 0; i < 4; ++i)
        Ps[(w * 16 + khi * 4 + i) * LV + nf * 16 + fr] =
            f2bf(__expf(sacc[nf][i]) * inv4[i]);

    // PV: A from wave-private Ps slab, B from Vs
#pragma unroll
    for (int ks = 0; ks < 128; ks += 32) {
      short8 ap = *(const short8*)&Ps[(w * 16 + fr) * LV + ks + khi * 8];
#pragma unroll
      for (int nv = 0; nv < 4; ++nv) {
        short8 bvv = *(const short8*)&Vs[(nv * 16 + fr) * LV + ks + khi * 8];
        pacc[nv] = __builtin_amdgcn_mfma_f32_16x16x32_bf16(ap, bvv, pacc[nv], 0, 0, 0);
      }
    }

    // coalesced score write: 2 rows x 512B per instr, 8 instrs per tile
    const int sr2 = lane >> 5, sc2 = (lane & 31) * 4;
#pragma unroll
    for (int ri = 0; ri < 8; ++ri) {
      int r = ri * 2 + sr2;
      s16x4 pv4 = *(const s16x4*)&Ps[(w * 16 + r) * LV + sc2];
      f32x4 o;
      o[0] = bf2f(pv4[0]); o[1] = bf2f(pv4[1]);
      o[2] = bf2f(pv4[2]); o[3] = bf2f(pv4[3]);
      *(f32x4*)&scores[((long)z << 20) + ((long)(qr + r) << 10) + t0 + sc2] = o;
    }
    __syncthreads();
  }

  // at[b][q][g*64 + d]
#pragma unroll
  for (int nv = 0; nv < 4; ++nv)
#pragma unroll
    for (int i = 0; i < 4; ++i)
      at[bqk + ((long)(qr + khi * 4 + i) << 10) + g * 64 + nv * 16 + fr] =
          f2bf(pacc[nv][i]);
}

// one wave per 1024-elem row
__global__ __launch_bounds__(256) void layernorm_rows(const float* __restrict__ X,
                                                      const float* __restrict__ gamma,
                                                      const float* __restrict__ beta,
                                                      float* __restrict__ O) {
  const int row = blockIdx.x * 4 + (threadIdx.x >> 6);
  const int lane = threadIdx.x & 63;
  const float* x = X + (long)row * 1024 + lane * 4;
  f32x4 v[4];
  float s = 0.f, sq = 0.f;
#pragma unroll
  for (int j = 0; j < 4; ++j) {
    v[j] = *(const f32x4*)(x + j * 256);
#pragma unroll
    for (int e = 0; e < 4; ++e) {
      s += v[j][e];
      sq += v[j][e] * v[j][e];
    }
  }
#pragma unroll
  for (int off = 32; off; off >>= 1) {
    s += __shfl_xor(s, off);
    sq += __shfl_xor(sq, off);
  }
  const float mu = s * (1.f / 1024.f);
  const float var = sq * (1.f / 1024.f) - mu * mu;
  const float rstd = rsqrtf(var + 1e-5f);
  float* o = O + (long)row * 1024 + lane * 4;
#pragma unroll
  for (int j = 0; j < 4; ++j) {
    f32x4 g = *(const f32x4*)(gamma + lane * 4 + j * 256);
    f32x4 be = *(const f32x4*)(beta + lane * 4 + j * 256);
    f32x4 r;
#pragma unroll
    for (int e = 0; e < 4; ++e) r[e] = (v[j][e] - mu) * rstd * g[e] + be[e];
    *(f32x4*)(o + j * 256) = r;
  }
}

extern "C" void kernel_launch(void* const* d_in, const int* in_sizes, int n_in,
                              void* d_out, int out_size, void* d_ws, size_t ws_size,
                              hipStream_t stream) {
  const float* Q = (const float*)d_in[0];
  const float* KV = (const float*)d_in[1];
  const float* Wq = (const float*)d_in[2];
  const float* bq = (const float*)d_in[3];
  const float* Wk = (const float*)d_in[4];
  const float* bk = (const float*)d_in[5];
  const float* Wv = (const float*)d_in[6];
  const float* bv = (const float*)d_in[7];
  const float* Wp = (const float*)d_in[8];
  const float* bp = (const float*)d_in[9];
  const float* gamma = (const float*)d_in[10];
  const float* beta = (const float*)d_in[11];

  float* out = (float*)d_out;                       // [4M] f32
  float* scores = out + (long)4 * 1024 * 1024;      // [64M] f32

  char* ws = (char*)d_ws;
  short* Wqb = (short*)(ws);                        // 2MB each
  short* Wkb = (short*)(ws + (2L << 20));
  short* Wvb = (short*)(ws + (4L << 20));
  short* Wpb = (short*)(ws + (6L << 20));           // permuted columns
  short* qb  = (short*)(ws + (8L << 20));           // 8MB (pre-scaled by 1/8)
  short* kb  = (short*)(ws + (16L << 20));          // 8MB
  short* vt  = (short*)(ws + (24L << 20));          // 8MB
  short* at  = (short*)(ws + (32L << 20));          // 8MB, feat = g*64+d
  float* pre = (float*)(ws + (40L << 20));          // 16MB
  float* bqs = (float*)(ws + (56L << 20));          // 4KB
  (void)ws_size; (void)in_sizes; (void)n_in; (void)out_size;

  // 1) weight conversions; fold 1/8 into Wq/bq
  convert_f32_bf16<<<512, 256, 0, stream>>>(Wq, Wqb, 131072, 0.125f);
  convert_f32_bf16<<<512, 256, 0, stream>>>(Wk, Wkb, 131072, 1.f);
  convert_f32_bf16<<<512, 256, 0, stream>>>(Wv, Wvb, 131072, 1.f);
  convert_permute_wp<<<1024, 256, 0, stream>>>(Wp, Wpb);
  scale_bias<<<4, 256, 0, stream>>>(bq, bqs);

  // 2) projections
  gemm_mfma<0, true, short><<<1024, 256, 0, stream>>>(
      Q, 1024, Wqb, 1024, qb, 1024, bqs, nullptr, 0, 1.f, 1024, 16);
  gemm_mfma<0, true, short><<<1024, 256, 0, stream>>>(
      KV, 1024, Wkb, 1024, kb, 1024, bk, nullptr, 0, 1.f, 1024, 16);
  gemm_mfma<1, true, short><<<1024, 256, 0, stream>>>(
      KV, 1024, Wvb, 1024, vt, 1024, bv, nullptr, 0, 1.f, 1024, 16);

  // 3) fused attention: scores (d_out) + at
  fused_attn<<<512, 512, 0, stream>>>(qb, kb, vt, scores, at);

  // 4) pre = at@Wpb^T + bp + Q
  gemm_mfma<0, false, float><<<1024, 256, 0, stream>>>(
      at, 1024, Wpb, 1024, pre, 1024, bp, Q, 1024, 1.f, 1024, 16);

  // 5) LayerNorm -> out
  layernorm_rows<<<1024, 256, 0, stream>>>(pre, gamma, beta, out);
}

// Round 6
// 198.453 us; speedup vs baseline: 1.9186x; 1.3015x over previous
//
#include <hip/hip_runtime.h>

typedef __attribute__((ext_vector_type(8))) short short8;
typedef __attribute__((ext_vector_type(4))) short s16x4;
typedef __attribute__((ext_vector_type(4))) float f32x4;

static __device__ __forceinline__ short f2bf(float x) {
  union { float f; unsigned u; } v; v.f = x;
  unsigned r = (v.u + 0x7fffu + ((v.u >> 16) & 1u)) >> 16;
  return (short)r;
}
static __device__ __forceinline__ float bf2f(short x) {
  union { unsigned u; float f; } v; v.u = ((unsigned)(unsigned short)x) << 16;
  return v.f;
}

// async 16B global -> LDS (dest: wave-uniform base + lane*16; src: per-lane)
static __device__ __forceinline__ void gld16(const short* g, short* l) {
  __builtin_amdgcn_global_load_lds(
      (const __attribute__((address_space(1))) unsigned*)g,
      (__attribute__((address_space(3))) unsigned*)l, 16, 0, 0);
}

// dst = bf16(src * scale), 8 elems/thread
__global__ __launch_bounds__(256) void convert_f32_bf16(const float* __restrict__ src,
                                                        short* __restrict__ dst, int n8,
                                                        float scale) {
  int i = blockIdx.x * 256 + threadIdx.x;
  if (i >= n8) return;
  const f32x4* s = (const f32x4*)(src + (long)i * 8);
  f32x4 a = s[0], b = s[1];
  short8 o;
  o[0] = f2bf(a[0] * scale); o[1] = f2bf(a[1] * scale);
  o[2] = f2bf(a[2] * scale); o[3] = f2bf(a[3] * scale);
  o[4] = f2bf(b[0] * scale); o[5] = f2bf(b[1] * scale);
  o[6] = f2bf(b[2] * scale); o[7] = f2bf(b[3] * scale);
  *(short8*)(dst + (long)i * 8) = o;
}

__global__ __launch_bounds__(256) void scale_bias(const float* __restrict__ src,
                                                  float* __restrict__ dst) {
  int i = blockIdx.x * 256 + threadIdx.x;
  dst[i] = src[i] * 0.125f;
}

// Wpb[o][g*64+d] = Wp[o][d*16+g]
__global__ __launch_bounds__(256) void convert_permute_wp(const float* __restrict__ src,
                                                          short* __restrict__ dst) {
  __shared__ float row[1024];
  const long o = blockIdx.x;
  *(f32x4*)&row[threadIdx.x * 4] = *(const f32x4*)(src + o * 1024 + threadIdx.x * 4);
  __syncthreads();
  const int f0 = threadIdx.x * 4;
  s16x4 t;
#pragma unroll
  for (int j = 0; j < 4; ++j) {
    int f = f0 + j;
    t[j] = f2bf(row[((f & 63) << 4) + (f >> 6)]);
  }
  *(s16x4*)(dst + o * 1024 + f0) = t;
}

// C[M,N] = scale * A[M,K] @ B[N,K]^T + bias + resid. A,B bf16.
// Staging: global_load_lds 16B, linear LDS, XOR-swizzled source chunks.
// OMODE 0: C[row*ldc + col]; OMODE 1: vt store C[(row>>10)<<20 | col<<10 | row&1023].
template <int OMODE, typename OutT>
__global__ __launch_bounds__(256, 4) void gemm_mfma(
    const short* __restrict__ A, int lda,
    const short* __restrict__ B, int ldb,
    OutT* __restrict__ Cb, int ldc,
    const float* __restrict__ bias,
    const float* __restrict__ resid, int ldres,
    float scale, int K, int nbn) {
  __shared__ short As[64 * 64];
  __shared__ short Bs[64 * 64];

  const int nwg = gridDim.x, cpx = nwg >> 3;
  int bid = blockIdx.x;
  bid = (bid & 7) * cpx + (bid >> 3);
  const int bn = (bid % nbn) * 64, bm = (bid / nbn) * 64;

  const int tid = threadIdx.x, lane = tid & 63, wave = tid >> 6;
  const int fr = lane & 15, khi = lane >> 4;

  f32x4 acc[4];
#pragma unroll
  for (int n = 0; n < 4; ++n) acc[n] = (f32x4){0.f, 0.f, 0.f, 0.f};

  for (int k0 = 0; k0 < K; k0 += 64) {
#pragma unroll
    for (int it = 0; it < 2; ++it) {
      int l = it * 256 + tid;
      int r = l >> 3, c = (l & 7) ^ (r & 7);
      gld16(A + (long)(bm + r) * lda + k0 + c * 8, &As[l * 8]);
      gld16(B + (long)(bn + r) * ldb + k0 + c * 8, &Bs[l * 8]);
    }
    __syncthreads();
#pragma unroll
    for (int ks = 0; ks < 64; ks += 32) {
      const int cc = (ks >> 3) + khi;
      const int ar = wave * 16 + fr;
      short8 af = *(const short8*)&As[ar * 64 + (cc ^ (ar & 7)) * 8];
#pragma unroll
      for (int n = 0; n < 4; ++n) {
        const int br = n * 16 + fr;
        short8 bf = *(const short8*)&Bs[br * 64 + (cc ^ (br & 7)) * 8];
        acc[n] = __builtin_amdgcn_mfma_f32_16x16x32_bf16(af, bf, acc[n], 0, 0, 0);
      }
    }
    __syncthreads();
  }

  const int col0 = lane & 15, row0 = (lane >> 4) * 4;
#pragma unroll
  for (int n = 0; n < 4; ++n) {
    int gcol = bn + n * 16 + col0;
    float bi = bias ? bias[gcol] : 0.f;
#pragma unroll
    for (int i = 0; i < 4; ++i) {
      int grow = bm + wave * 16 + row0 + i;
      float v = acc[n][i] * scale + bi;
      if (resid) v += resid[(long)grow * ldres + gcol];
      long addr;
      if (OMODE == 0)
        addr = (long)grow * ldc + gcol;
      else
        addr = ((long)(grow >> 10) << 20) + ((long)gcol << 10) + (grow & 1023);
      if constexpr (sizeof(OutT) == 2)
        Cb[addr] = (OutT)f2bf(v);
      else
        Cb[addr] = v;
    }
  }
}

// Fused attention v6: block = 512 thr (8 waves) per (z, 128 q-rows); wave owns 16
// q-rows x all keys. KT=64 tiles; Ks/Vs linear + XOR-source-swizzled global_load_lds;
// sum-only softmax; scores written coalesced via bf16 Ps tile. LDS 34.8 KB.
__global__ __launch_bounds__(512, 6) void fused_attn(
    const short* __restrict__ qb,   // [4][1024][1024] bf16, feat = g*64+d (x1/8)
    const short* __restrict__ kb,   // [4][1024][1024] bf16, feat = g*64+d
    const short* __restrict__ vt,   // [4][1024][1024] bf16, vt[b][d*16+g][t]
    float* __restrict__ scores,     // [64][1024][1024] f32
    short* __restrict__ at) {       // [4][1024][1024] bf16, feat = g*64+d
  constexpr int LP = 72;
  __shared__ short Ks[64 * 64];     // 8 KB
  __shared__ short Vs[64 * 64];     // 8 KB
  __shared__ short Ps[128 * LP];    // 18 KB (wave-private 16-row slabs)

  int bid = blockIdx.x;
  bid = (bid & 7) * 64 + (bid >> 3);      // 8 z's per XCD
  const int z = bid >> 3, b = z >> 4, g = z & 15;
  const int q0 = (bid & 7) * 128;

  const int tid = threadIdx.x, lane = tid & 63, w = tid >> 6;
  const int fr = lane & 15, khi = lane >> 4;
  const long bqk = (long)b << 20;
  const int qr = q0 + w * 16;

  const short* qrow = qb + bqk + (long)(qr + fr) * 1024 + g * 64 + khi * 8;
  const short8 aq0 = *(const short8*)qrow;
  const short8 aq1 = *(const short8*)(qrow + 32);
  const short* kgp = kb + bqk + g * 64;
  const short* vgp = vt + bqk;

  // staging: 512 chunks of 16B; thread tid -> LDS chunk tid, source chunk XOR'd
  const int srr = tid >> 3, ssc = ((tid & 7) ^ (srr & 7)) * 8;

  // ---- pass 1: exp-sums ----
  float s4[4] = {0.f, 0.f, 0.f, 0.f};
  for (int t0 = 0; t0 < 1024; t0 += 64) {
    gld16(kgp + (long)(t0 + srr) * 1024 + ssc, &Ks[tid * 8]);
    __syncthreads();
    f32x4 sacc[4];
#pragma unroll
    for (int nf = 0; nf < 4; ++nf) sacc[nf] = (f32x4){0.f, 0.f, 0.f, 0.f};
#pragma unroll
    for (int nf = 0; nf < 4; ++nf) {
      const int r2 = nf * 16 + fr;
      short8 b0 = *(const short8*)&Ks[r2 * 64 + (khi ^ (r2 & 7)) * 8];
      short8 b1 = *(const short8*)&Ks[r2 * 64 + ((khi + 4) ^ (r2 & 7)) * 8];
      sacc[nf] = __builtin_amdgcn_mfma_f32_16x16x32_bf16(aq0, b0, sacc[nf], 0, 0, 0);
      sacc[nf] = __builtin_amdgcn_mfma_f32_16x16x32_bf16(aq1, b1, sacc[nf], 0, 0, 0);
    }
#pragma unroll
    for (int nf = 0; nf < 4; ++nf)
#pragma unroll
      for (int i = 0; i < 4; ++i) s4[i] += __expf(sacc[nf][i]);
    __syncthreads();
  }
#pragma unroll
  for (int i = 0; i < 4; ++i) {
    s4[i] += __shfl_xor(s4[i], 1);
    s4[i] += __shfl_xor(s4[i], 2);
    s4[i] += __shfl_xor(s4[i], 4);
    s4[i] += __shfl_xor(s4[i], 8);
  }
  float inv4[4];
#pragma unroll
  for (int i = 0; i < 4; ++i) inv4[i] = 1.f / s4[i];

  // ---- pass 2: recompute, P -> Ps, PV, coalesced score write ----
  f32x4 pacc[4];
#pragma unroll
  for (int nv = 0; nv < 4; ++nv) pacc[nv] = (f32x4){0.f, 0.f, 0.f, 0.f};

  for (int t0 = 0; t0 < 1024; t0 += 64) {
    gld16(kgp + (long)(t0 + srr) * 1024 + ssc, &Ks[tid * 8]);
    gld16(vgp + ((long)(srr * 16 + g) << 10) + t0 + ssc, &Vs[tid * 8]);
    __syncthreads();
    f32x4 sacc[4];
#pragma unroll
    for (int nf = 0; nf < 4; ++nf) sacc[nf] = (f32x4){0.f, 0.f, 0.f, 0.f};
#pragma unroll
    for (int nf = 0; nf < 4; ++nf) {
      const int r2 = nf * 16 + fr;
      short8 b0 = *(const short8*)&Ks[r2 * 64 + (khi ^ (r2 & 7)) * 8];
      short8 b1 = *(const short8*)&Ks[r2 * 64 + ((khi + 4) ^ (r2 & 7)) * 8];
      sacc[nf] = __builtin_amdgcn_mfma_f32_16x16x32_bf16(aq0, b0, sacc[nf], 0, 0, 0);
      sacc[nf] = __builtin_amdgcn_mfma_f32_16x16x32_bf16(aq1, b1, sacc[nf], 0, 0, 0);
    }
#pragma unroll
    for (int nf = 0; nf < 4; ++nf)
#pragma unroll
      for (int i = 0; i < 4; ++i)
        Ps[(w * 16 + khi * 4 + i) * LP + nf * 16 + fr] =
            f2bf(__expf(sacc[nf][i]) * inv4[i]);

    // PV: A from own Ps slab, B from Vs (no barrier: Ps rows wave-private)
#pragma unroll
    for (int ks = 0; ks < 64; ks += 32) {
      const int cc = (ks >> 3) + khi;
      short8 ap = *(const short8*)&Ps[(w * 16 + fr) * LP + ks + khi * 8];
#pragma unroll
      for (int nv = 0; nv < 4; ++nv) {
        const int dr = nv * 16 + fr;
        short8 bvv = *(const short8*)&Vs[dr * 64 + (cc ^ (dr & 7)) * 8];
        pacc[nv] = __builtin_amdgcn_mfma_f32_16x16x32_bf16(ap, bvv, pacc[nv], 0, 0, 0);
      }
    }

    // coalesced score write: per wave 16 rows x 256B
#pragma unroll
    for (int ri = 0; ri < 4; ++ri) {
      const int row = ri * 4 + khi;
      s16x4 pv4 = *(const s16x4*)&Ps[(w * 16 + row) * LP + fr * 4];
      f32x4 o;
      o[0] = bf2f(pv4[0]); o[1] = bf2f(pv4[1]);
      o[2] = bf2f(pv4[2]); o[3] = bf2f(pv4[3]);
      *(f32x4*)&scores[((long)z << 20) + ((long)(qr + row) << 10) + t0 + fr * 4] = o;
    }
    __syncthreads();
  }

  // at[b][q][g*64 + d]
#pragma unroll
  for (int nv = 0; nv < 4; ++nv)
#pragma unroll
    for (int i = 0; i < 4; ++i)
      at[bqk + ((long)(qr + khi * 4 + i) << 10) + g * 64 + nv * 16 + fr] =
          f2bf(pacc[nv][i]);
}

// one wave per 1024-elem row
__global__ __launch_bounds__(256) void layernorm_rows(const float* __restrict__ X,
                                                      const float* __restrict__ gamma,
                                                      const float* __restrict__ beta,
                                                      float* __restrict__ O) {
  const int row = blockIdx.x * 4 + (threadIdx.x >> 6);
  const int lane = threadIdx.x & 63;
  const float* x = X + (long)row * 1024 + lane * 4;
  f32x4 v[4];
  float s = 0.f, sq = 0.f;
#pragma unroll
  for (int j = 0; j < 4; ++j) {
    v[j] = *(const f32x4*)(x + j * 256);
#pragma unroll
    for (int e = 0; e < 4; ++e) {
      s += v[j][e];
      sq += v[j][e] * v[j][e];
    }
  }
#pragma unroll
  for (int off = 32; off; off >>= 1) {
    s += __shfl_xor(s, off);
    sq += __shfl_xor(sq, off);
  }
  const float mu = s * (1.f / 1024.f);
  const float var = sq * (1.f / 1024.f) - mu * mu;
  const float rstd = rsqrtf(var + 1e-5f);
  float* o = O + (long)row * 1024 + lane * 4;
#pragma unroll
  for (int j = 0; j < 4; ++j) {
    f32x4 g = *(const f32x4*)(gamma + lane * 4 + j * 256);
    f32x4 be = *(const f32x4*)(beta + lane * 4 + j * 256);
    f32x4 r;
#pragma unroll
    for (int e = 0; e < 4; ++e) r[e] = (v[j][e] - mu) * rstd * g[e] + be[e];
    *(f32x4*)(o + j * 256) = r;
  }
}

extern "C" void kernel_launch(void* const* d_in, const int* in_sizes, int n_in,
                              void* d_out, int out_size, void* d_ws, size_t ws_size,
                              hipStream_t stream) {
  const float* Q = (const float*)d_in[0];
  const float* KV = (const float*)d_in[1];
  const float* Wq = (const float*)d_in[2];
  const float* bq = (const float*)d_in[3];
  const float* Wk = (const float*)d_in[4];
  const float* bk = (const float*)d_in[5];
  const float* Wv = (const float*)d_in[6];
  const float* bv = (const float*)d_in[7];
  const float* Wp = (const float*)d_in[8];
  const float* bp = (const float*)d_in[9];
  const float* gamma = (const float*)d_in[10];
  const float* beta = (const float*)d_in[11];

  float* out = (float*)d_out;                       // [4M] f32
  float* scores = out + (long)4 * 1024 * 1024;      // [64M] f32

  char* ws = (char*)d_ws;
  short* Wqb = (short*)(ws);                        // 2MB each
  short* Wkb = (short*)(ws + (2L << 20));
  short* Wvb = (short*)(ws + (4L << 20));
  short* Wpb = (short*)(ws + (6L << 20));           // permuted columns
  short* qb  = (short*)(ws + (8L << 20));           // 8MB (pre-scaled by 1/8)
  short* kb  = (short*)(ws + (16L << 20));          // 8MB
  short* vt  = (short*)(ws + (24L << 20));          // 8MB
  short* at  = (short*)(ws + (32L << 20));          // 8MB, feat = g*64+d
  float* pre = (float*)(ws + (40L << 20));          // 16MB (written after attn)
  short* Qb  = (short*)(ws + (40L << 20));          // 8MB  (dead before pre)
  short* KVb = (short*)(ws + (48L << 20));          // 8MB  (dead before pre)
  float* bqs = (float*)(ws + (56L << 20));          // 4KB
  (void)ws_size; (void)in_sizes; (void)n_in; (void)out_size;

  // 1) conversions; fold 1/8 into Wq/bq
  convert_f32_bf16<<<2048, 256, 0, stream>>>(Q, Qb, 524288, 1.f);
  convert_f32_bf16<<<2048, 256, 0, stream>>>(KV, KVb, 524288, 1.f);
  convert_f32_bf16<<<512, 256, 0, stream>>>(Wq, Wqb, 131072, 0.125f);
  convert_f32_bf16<<<512, 256, 0, stream>>>(Wk, Wkb, 131072, 1.f);
  convert_f32_bf16<<<512, 256, 0, stream>>>(Wv, Wvb, 131072, 1.f);
  convert_permute_wp<<<1024, 256, 0, stream>>>(Wp, Wpb);
  scale_bias<<<4, 256, 0, stream>>>(bq, bqs);

  // 2) projections
  gemm_mfma<0, short><<<1024, 256, 0, stream>>>(
      Qb, 1024, Wqb, 1024, qb, 1024, bqs, nullptr, 0, 1.f, 1024, 16);
  gemm_mfma<0, short><<<1024, 256, 0, stream>>>(
      KVb, 1024, Wkb, 1024, kb, 1024, bk, nullptr, 0, 1.f, 1024, 16);
  gemm_mfma<1, short><<<1024, 256, 0, stream>>>(
      KVb, 1024, Wvb, 1024, vt, 1024, bv, nullptr, 0, 1.f, 1024, 16);

  // 3) fused attention: scores (d_out) + at
  fused_attn<<<512, 512, 0, stream>>>(qb, kb, vt, scores, at);

  // 4) pre = at@Wpb^T + bp + Q
  gemm_mfma<0, float><<<1024, 256, 0, stream>>>(
      at, 1024, Wpb, 1024, pre, 1024, bp, Q, 1024, 1.f, 1024, 16);

  // 5) LayerNorm -> out
  layernorm_rows<<<1024, 256, 0, stream>>>(pre, gamma, beta, out);
}

// Round 7
// 193.127 us; speedup vs baseline: 1.9715x; 1.0276x over previous
//
#include <hip/hip_runtime.h>

typedef __attribute__((ext_vector_type(8))) short short8;
typedef __attribute__((ext_vector_type(4))) short s16x4;
typedef __attribute__((ext_vector_type(4))) float f32x4;

static __device__ __forceinline__ short f2bf(float x) {
  union { float f; unsigned u; } v; v.f = x;
  unsigned r = (v.u + 0x7fffu + ((v.u >> 16) & 1u)) >> 16;
  return (short)r;
}
static __device__ __forceinline__ float bf2f(short x) {
  union { unsigned u; float f; } v; v.u = ((unsigned)(unsigned short)x) << 16;
  return v.f;
}

// async 16B global -> LDS (dest: wave-uniform base + lane*16; src: per-lane)
static __device__ __forceinline__ void gld16(const short* g, short* l) {
  __builtin_amdgcn_global_load_lds(
      (const __attribute__((address_space(1))) unsigned*)g,
      (__attribute__((address_space(3))) unsigned*)l, 16, 0, 0);
}

// dst = bf16(src * scale), 8 elems/thread
__global__ __launch_bounds__(256) void convert_f32_bf16(const float* __restrict__ src,
                                                        short* __restrict__ dst, int n8,
                                                        float scale) {
  int i = blockIdx.x * 256 + threadIdx.x;
  if (i >= n8) return;
  const f32x4* s = (const f32x4*)(src + (long)i * 8);
  f32x4 a = s[0], b = s[1];
  short8 o;
  o[0] = f2bf(a[0] * scale); o[1] = f2bf(a[1] * scale);
  o[2] = f2bf(a[2] * scale); o[3] = f2bf(a[3] * scale);
  o[4] = f2bf(b[0] * scale); o[5] = f2bf(b[1] * scale);
  o[6] = f2bf(b[2] * scale); o[7] = f2bf(b[3] * scale);
  *(short8*)(dst + (long)i * 8) = o;
}

__global__ __launch_bounds__(256) void scale_bias(const float* __restrict__ src,
                                                  float* __restrict__ dst) {
  int i = blockIdx.x * 256 + threadIdx.x;
  dst[i] = src[i] * 0.125f;
}

// Wpb[o][g*64+d] = Wp[o][d*16+g]
__global__ __launch_bounds__(256) void convert_permute_wp(const float* __restrict__ src,
                                                          short* __restrict__ dst) {
  __shared__ float row[1024];
  const long o = blockIdx.x;
  *(f32x4*)&row[threadIdx.x * 4] = *(const f32x4*)(src + o * 1024 + threadIdx.x * 4);
  __syncthreads();
  const int f0 = threadIdx.x * 4;
  s16x4 t;
#pragma unroll
  for (int j = 0; j < 4; ++j) {
    int f = f0 + j;
    t[j] = f2bf(row[((f & 63) << 4) + (f >> 6)]);
  }
  *(s16x4*)(dst + o * 1024 + f0) = t;
}

// C[M,N] = scale * A[M,K] @ B[N,K]^T + bias + resid. A,B bf16.
// global_load_lds staging, double-buffered (2-phase pipeline: issue next tile
// before computing current; single barrier per K-step drains it).
// OMODE 0: C[row*ldc + col]; OMODE 1: vt store C[(row>>10)<<20 | col<<10 | row&1023].
template <int OMODE, typename OutT>
__global__ __launch_bounds__(256, 4) void gemm_mfma(
    const short* __restrict__ A, int lda,
    const short* __restrict__ B, int ldb,
    OutT* __restrict__ Cb, int ldc,
    const float* __restrict__ bias,
    const float* __restrict__ resid, int ldres,
    float scale, int K, int nbn) {
  __shared__ short As[2][64 * 64];
  __shared__ short Bs[2][64 * 64];

  const int nwg = gridDim.x, cpx = nwg >> 3;
  int bid = blockIdx.x;
  bid = (bid & 7) * cpx + (bid >> 3);
  const int bn = (bid % nbn) * 64, bm = (bid / nbn) * 64;

  const int tid = threadIdx.x, lane = tid & 63, wave = tid >> 6;
  const int fr = lane & 15, khi = lane >> 4;

  f32x4 acc[4];
#pragma unroll
  for (int n = 0; n < 4; ++n) acc[n] = (f32x4){0.f, 0.f, 0.f, 0.f};

  auto stage = [&](int buf, int k0) {
#pragma unroll
    for (int it = 0; it < 2; ++it) {
      int l = it * 256 + tid;
      int r = l >> 3, c = (l & 7) ^ (r & 7);
      gld16(A + (long)(bm + r) * lda + k0 + c * 8, &As[buf][l * 8]);
      gld16(B + (long)(bn + r) * ldb + k0 + c * 8, &Bs[buf][l * 8]);
    }
  };

  stage(0, 0);
  __syncthreads();
  int cur = 0;
  for (int k0 = 0; k0 < K; k0 += 64) {
    if (k0 + 64 < K) stage(cur ^ 1, k0 + 64);
#pragma unroll
    for (int ks = 0; ks < 64; ks += 32) {
      const int cc = (ks >> 3) + khi;
      const int ar = wave * 16 + fr;
      short8 af = *(const short8*)&As[cur][ar * 64 + (cc ^ (ar & 7)) * 8];
#pragma unroll
      for (int n = 0; n < 4; ++n) {
        const int br = n * 16 + fr;
        short8 bf = *(const short8*)&Bs[cur][br * 64 + (cc ^ (br & 7)) * 8];
        acc[n] = __builtin_amdgcn_mfma_f32_16x16x32_bf16(af, bf, acc[n], 0, 0, 0);
      }
    }
    __syncthreads();
    cur ^= 1;
  }

  const int col0 = lane & 15, row0 = (lane >> 4) * 4;
#pragma unroll
  for (int n = 0; n < 4; ++n) {
    int gcol = bn + n * 16 + col0;
    float bi = bias ? bias[gcol] : 0.f;
#pragma unroll
    for (int i = 0; i < 4; ++i) {
      int grow = bm + wave * 16 + row0 + i;
      float v = acc[n][i] * scale + bi;
      if (resid) v += resid[(long)grow * ldres + gcol];
      long addr;
      if (OMODE == 0)
        addr = (long)grow * ldc + gcol;
      else
        addr = ((long)(grow >> 10) << 20) + ((long)gcol << 10) + (grow & 1023);
      if constexpr (sizeof(OutT) == 2)
        Cb[addr] = (OutT)f2bf(v);
      else
        Cb[addr] = v;
    }
  }
}

// Fused attention v7: 512 thr (8 waves) per (z, 128 q-rows); wave owns 16 q-rows.
// KT=64 tiles, double-buffered K/V staging (2-phase pipeline, 1 barrier/tile);
// sum-only softmax; scores written coalesced via bf16 Ps tile. LDS 50 KB.
__global__ __launch_bounds__(512, 6) void fused_attn(
    const short* __restrict__ qb,   // [4][1024][1024] bf16, feat = g*64+d (x1/8)
    const short* __restrict__ kb,   // [4][1024][1024] bf16, feat = g*64+d
    const short* __restrict__ vt,   // [4][1024][1024] bf16, vt[b][d*16+g][t]
    float* __restrict__ scores,     // [64][1024][1024] f32
    short* __restrict__ at) {       // [4][1024][1024] bf16, feat = g*64+d
  constexpr int LP = 72;
  __shared__ short Ks[2][64 * 64];  // 16 KB
  __shared__ short Vs[2][64 * 64];  // 16 KB
  __shared__ short Ps[128 * LP];    // 18 KB (wave-private 16-row slabs)

  int bid = blockIdx.x;
  bid = (bid & 7) * 64 + (bid >> 3);      // 8 z's per XCD
  const int z = bid >> 3, b = z >> 4, g = z & 15;
  const int q0 = (bid & 7) * 128;

  const int tid = threadIdx.x, lane = tid & 63, w = tid >> 6;
  const int fr = lane & 15, khi = lane >> 4;
  const long bqk = (long)b << 20;
  const int qr = q0 + w * 16;

  const short* qrow = qb + bqk + (long)(qr + fr) * 1024 + g * 64 + khi * 8;
  const short8 aq0 = *(const short8*)qrow;
  const short8 aq1 = *(const short8*)(qrow + 32);
  const short* kgp = kb + bqk + g * 64;
  const short* vgp = vt + bqk;

  // staging: 512 chunks of 16B; LDS chunk tid, source chunk XOR'd by row
  const int srr = tid >> 3, ssc = ((tid & 7) ^ (srr & 7)) * 8;

  // ---- pass 1: exp-sums (K double-buffered) ----
  float s4[4] = {0.f, 0.f, 0.f, 0.f};
  gld16(kgp + (long)srr * 1024 + ssc, &Ks[0][tid * 8]);
  __syncthreads();
  int cur = 0;
  for (int t0 = 0; t0 < 1024; t0 += 64) {
    if (t0 < 960)
      gld16(kgp + (long)(t0 + 64 + srr) * 1024 + ssc, &Ks[cur ^ 1][tid * 8]);
    f32x4 sacc[4];
#pragma unroll
    for (int nf = 0; nf < 4; ++nf) sacc[nf] = (f32x4){0.f, 0.f, 0.f, 0.f};
#pragma unroll
    for (int nf = 0; nf < 4; ++nf) {
      const int r2 = nf * 16 + fr;
      short8 b0 = *(const short8*)&Ks[cur][r2 * 64 + (khi ^ (r2 & 7)) * 8];
      short8 b1 = *(const short8*)&Ks[cur][r2 * 64 + ((khi + 4) ^ (r2 & 7)) * 8];
      sacc[nf] = __builtin_amdgcn_mfma_f32_16x16x32_bf16(aq0, b0, sacc[nf], 0, 0, 0);
      sacc[nf] = __builtin_amdgcn_mfma_f32_16x16x32_bf16(aq1, b1, sacc[nf], 0, 0, 0);
    }
#pragma unroll
    for (int nf = 0; nf < 4; ++nf)
#pragma unroll
      for (int i = 0; i < 4; ++i) s4[i] += __expf(sacc[nf][i]);
    __syncthreads();
    cur ^= 1;
  }
#pragma unroll
  for (int i = 0; i < 4; ++i) {
    s4[i] += __shfl_xor(s4[i], 1);
    s4[i] += __shfl_xor(s4[i], 2);
    s4[i] += __shfl_xor(s4[i], 4);
    s4[i] += __shfl_xor(s4[i], 8);
  }
  float inv4[4];
#pragma unroll
  for (int i = 0; i < 4; ++i) inv4[i] = 1.f / s4[i];

  // ---- pass 2: recompute, P -> Ps, PV, coalesced score write (K+V dbuf) ----
  f32x4 pacc[4];
#pragma unroll
  for (int nv = 0; nv < 4; ++nv) pacc[nv] = (f32x4){0.f, 0.f, 0.f, 0.f};

  gld16(kgp + (long)srr * 1024 + ssc, &Ks[0][tid * 8]);
  gld16(vgp + ((long)(srr * 16 + g) << 10) + ssc, &Vs[0][tid * 8]);
  __syncthreads();
  cur = 0;
  for (int t0 = 0; t0 < 1024; t0 += 64) {
    if (t0 < 960) {
      gld16(kgp + (long)(t0 + 64 + srr) * 1024 + ssc, &Ks[cur ^ 1][tid * 8]);
      gld16(vgp + ((long)(srr * 16 + g) << 10) + t0 + 64 + ssc, &Vs[cur ^ 1][tid * 8]);
    }
    f32x4 sacc[4];
#pragma unroll
    for (int nf = 0; nf < 4; ++nf) sacc[nf] = (f32x4){0.f, 0.f, 0.f, 0.f};
#pragma unroll
    for (int nf = 0; nf < 4; ++nf) {
      const int r2 = nf * 16 + fr;
      short8 b0 = *(const short8*)&Ks[cur][r2 * 64 + (khi ^ (r2 & 7)) * 8];
      short8 b1 = *(const short8*)&Ks[cur][r2 * 64 + ((khi + 4) ^ (r2 & 7)) * 8];
      sacc[nf] = __builtin_amdgcn_mfma_f32_16x16x32_bf16(aq0, b0, sacc[nf], 0, 0, 0);
      sacc[nf] = __builtin_amdgcn_mfma_f32_16x16x32_bf16(aq1, b1, sacc[nf], 0, 0, 0);
    }
#pragma unroll
    for (int nf = 0; nf < 4; ++nf)
#pragma unroll
      for (int i = 0; i < 4; ++i)
        Ps[(w * 16 + khi * 4 + i) * LP + nf * 16 + fr] =
            f2bf(__expf(sacc[nf][i]) * inv4[i]);

    // PV: A from own Ps slab, B from Vs[cur] (Ps rows wave-private)
#pragma unroll
    for (int ks = 0; ks < 64; ks += 32) {
      const int cc = (ks >> 3) + khi;
      short8 ap = *(const short8*)&Ps[(w * 16 + fr) * LP + ks + khi * 8];
#pragma unroll
      for (int nv = 0; nv < 4; ++nv) {
        const int dr = nv * 16 + fr;
        short8 bvv = *(const short8*)&Vs[cur][dr * 64 + (cc ^ (dr & 7)) * 8];
        pacc[nv] = __builtin_amdgcn_mfma_f32_16x16x32_bf16(ap, bvv, pacc[nv], 0, 0, 0);
      }
    }

    // coalesced score write: per wave 16 rows x 256B
#pragma unroll
    for (int ri = 0; ri < 4; ++ri) {
      const int row = ri * 4 + khi;
      s16x4 pv4 = *(const s16x4*)&Ps[(w * 16 + row) * LP + fr * 4];
      f32x4 o;
      o[0] = bf2f(pv4[0]); o[1] = bf2f(pv4[1]);
      o[2] = bf2f(pv4[2]); o[3] = bf2f(pv4[3]);
      *(f32x4*)&scores[((long)z << 20) + ((long)(qr + row) << 10) + t0 + fr * 4] = o;
    }
    __syncthreads();
    cur ^= 1;
  }

  // at[b][q][g*64 + d]
#pragma unroll
  for (int nv = 0; nv < 4; ++nv)
#pragma unroll
    for (int i = 0; i < 4; ++i)
      at[bqk + ((long)(qr + khi * 4 + i) << 10) + g * 64 + nv * 16 + fr] =
          f2bf(pacc[nv][i]);
}

// one wave per 1024-elem row
__global__ __launch_bounds__(256) void layernorm_rows(const float* __restrict__ X,
                                                      const float* __restrict__ gamma,
                                                      const float* __restrict__ beta,
                                                      float* __restrict__ O) {
  const int row = blockIdx.x * 4 + (threadIdx.x >> 6);
  const int lane = threadIdx.x & 63;
  const float* x = X + (long)row * 1024 + lane * 4;
  f32x4 v[4];
  float s = 0.f, sq = 0.f;
#pragma unroll
  for (int j = 0; j < 4; ++j) {
    v[j] = *(const f32x4*)(x + j * 256);
#pragma unroll
    for (int e = 0; e < 4; ++e) {
      s += v[j][e];
      sq += v[j][e] * v[j][e];
    }
  }
#pragma unroll
  for (int off = 32; off; off >>= 1) {
    s += __shfl_xor(s, off);
    sq += __shfl_xor(sq, off);
  }
  const float mu = s * (1.f / 1024.f);
  const float var = sq * (1.f / 1024.f) - mu * mu;
  const float rstd = rsqrtf(var + 1e-5f);
  float* o = O + (long)row * 1024 + lane * 4;
#pragma unroll
  for (int j = 0; j < 4; ++j) {
    f32x4 g = *(const f32x4*)(gamma + lane * 4 + j * 256);
    f32x4 be = *(const f32x4*)(beta + lane * 4 + j * 256);
    f32x4 r;
#pragma unroll
    for (int e = 0; e < 4; ++e) r[e] = (v[j][e] - mu) * rstd * g[e] + be[e];
    *(f32x4*)(o + j * 256) = r;
  }
}

extern "C" void kernel_launch(void* const* d_in, const int* in_sizes, int n_in,
                              void* d_out, int out_size, void* d_ws, size_t ws_size,
                              hipStream_t stream) {
  const float* Q = (const float*)d_in[0];
  const float* KV = (const float*)d_in[1];
  const float* Wq = (const float*)d_in[2];
  const float* bq = (const float*)d_in[3];
  const float* Wk = (const float*)d_in[4];
  const float* bk = (const float*)d_in[5];
  const float* Wv = (const float*)d_in[6];
  const float* bv = (const float*)d_in[7];
  const float* Wp = (const float*)d_in[8];
  const float* bp = (const float*)d_in[9];
  const float* gamma = (const float*)d_in[10];
  const float* beta = (const float*)d_in[11];

  float* out = (float*)d_out;                       // [4M] f32
  float* scores = out + (long)4 * 1024 * 1024;      // [64M] f32

  char* ws = (char*)d_ws;
  short* Wqb = (short*)(ws);                        // 2MB each
  short* Wkb = (short*)(ws + (2L << 20));
  short* Wvb = (short*)(ws + (4L << 20));
  short* Wpb = (short*)(ws + (6L << 20));           // permuted columns
  short* qb  = (short*)(ws + (8L << 20));           // 8MB (pre-scaled by 1/8)
  short* kb  = (short*)(ws + (16L << 20));          // 8MB
  short* vt  = (short*)(ws + (24L << 20));          // 8MB
  short* at  = (short*)(ws + (32L << 20));          // 8MB, feat = g*64+d
  float* pre = (float*)(ws + (40L << 20));          // 16MB (written after attn)
  short* Qb  = (short*)(ws + (40L << 20));          // 8MB  (dead before pre)
  short* KVb = (short*)(ws + (48L << 20));          // 8MB  (dead before pre)
  float* bqs = (float*)(ws + (56L << 20));          // 4KB
  (void)ws_size; (void)in_sizes; (void)n_in; (void)out_size;

  // 1) conversions; fold 1/8 into Wq/bq
  convert_f32_bf16<<<2048, 256, 0, stream>>>(Q, Qb, 524288, 1.f);
  convert_f32_bf16<<<2048, 256, 0, stream>>>(KV, KVb, 524288, 1.f);
  convert_f32_bf16<<<512, 256, 0, stream>>>(Wq, Wqb, 131072, 0.125f);
  convert_f32_bf16<<<512, 256, 0, stream>>>(Wk, Wkb, 131072, 1.f);
  convert_f32_bf16<<<512, 256, 0, stream>>>(Wv, Wvb, 131072, 1.f);
  convert_permute_wp<<<1024, 256, 0, stream>>>(Wp, Wpb);
  scale_bias<<<4, 256, 0, stream>>>(bq, bqs);

  // 2) projections
  gemm_mfma<0, short><<<1024, 256, 0, stream>>>(
      Qb, 1024, Wqb, 1024, qb, 1024, bqs, nullptr, 0, 1.f, 1024, 16);
  gemm_mfma<0, short><<<1024, 256, 0, stream>>>(
      KVb, 1024, Wkb, 1024, kb, 1024, bk, nullptr, 0, 1.f, 1024, 16);
  gemm_mfma<1, short><<<1024, 256, 0, stream>>>(
      KVb, 1024, Wvb, 1024, vt, 1024, bv, nullptr, 0, 1.f, 1024, 16);

  // 3) fused attention: scores (d_out) + at
  fused_attn<<<512, 512, 0, stream>>>(qb, kb, vt, scores, at);

  // 4) pre = at@Wpb^T + bp + Q
  gemm_mfma<0, float><<<1024, 256, 0, stream>>>(
      at, 1024, Wpb, 1024, pre, 1024, bp, Q, 1024, 1.f, 1024, 16);

  // 5) LayerNorm -> out
  layernorm_rows<<<1024, 256, 0, stream>>>(pre, gamma, beta, out);
}

// Round 8
// 179.242 us; speedup vs baseline: 2.1242x; 1.0775x over previous
//
#include <hip/hip_runtime.h>

typedef __attribute__((ext_vector_type(8))) short short8;
typedef __attribute__((ext_vector_type(4))) short s16x4;
typedef __attribute__((ext_vector_type(4))) float f32x4;

static __device__ __forceinline__ short f2bf(float x) {
  union { float f; unsigned u; } v; v.f = x;
  unsigned r = (v.u + 0x7fffu + ((v.u >> 16) & 1u)) >> 16;
  return (short)r;
}
static __device__ __forceinline__ float bf2f(short x) {
  union { unsigned u; float f; } v; v.u = ((unsigned)(unsigned short)x) << 16;
  return v.f;
}

// async 16B global -> LDS (dest: wave-uniform base + lane*16; src: per-lane)
static __device__ __forceinline__ void gld16(const short* g, short* l) {
  __builtin_amdgcn_global_load_lds(
      (const __attribute__((address_space(1))) unsigned*)g,
      (__attribute__((address_space(3))) unsigned*)l, 16, 0, 0);
}

// ---------------- prep: all conversions in one launch ----------------
static __device__ __forceinline__ void conv8(const float* __restrict__ src,
                                             short* __restrict__ dst, int i,
                                             float scale) {
  const f32x4* s = (const f32x4*)(src + (long)i * 8);
  f32x4 a = s[0], b = s[1];
  short8 o;
  o[0] = f2bf(a[0] * scale); o[1] = f2bf(a[1] * scale);
  o[2] = f2bf(a[2] * scale); o[3] = f2bf(a[3] * scale);
  o[4] = f2bf(b[0] * scale); o[5] = f2bf(b[1] * scale);
  o[6] = f2bf(b[2] * scale); o[7] = f2bf(b[3] * scale);
  *(short8*)(dst + (long)i * 8) = o;
}

__global__ __launch_bounds__(256) void prep(
    const float* __restrict__ Q, const float* __restrict__ KV,
    const float* __restrict__ Wq, const float* __restrict__ Wk,
    const float* __restrict__ Wv, const float* __restrict__ Wp,
    const float* __restrict__ bq,
    short* __restrict__ Qb, short* __restrict__ KVb,
    short* __restrict__ Wqb, short* __restrict__ Wkb,
    short* __restrict__ Wvb, short* __restrict__ Wpb,
    float* __restrict__ bqs) {
  const int blk = blockIdx.x, tid = threadIdx.x;
  if (blk < 2048) {
    conv8(Q, Qb, blk * 256 + tid, 1.f);
  } else if (blk < 4096) {
    conv8(KV, KVb, (blk - 2048) * 256 + tid, 1.f);
  } else if (blk < 4608) {
    conv8(Wq, Wqb, (blk - 4096) * 256 + tid, 0.125f);   // fold 1/8 into Wq
  } else if (blk < 5120) {
    conv8(Wk, Wkb, (blk - 4608) * 256 + tid, 1.f);
  } else if (blk < 5632) {
    conv8(Wv, Wvb, (blk - 5120) * 256 + tid, 1.f);
  } else if (blk < 6656) {
    // Wpb[o][g*64+d] = Wp[o][d*16+g]
    __shared__ float row[1024];
    const long o = blk - 5632;
    *(f32x4*)&row[tid * 4] = *(const f32x4*)(Wp + o * 1024 + tid * 4);
    __syncthreads();
    const int f0 = tid * 4;
    s16x4 t;
#pragma unroll
    for (int j = 0; j < 4; ++j) {
      int f = f0 + j;
      t[j] = f2bf(row[((f & 63) << 4) + (f >> 6)]);
    }
    *(s16x4*)(Wpb + o * 1024 + f0) = t;
  } else {
    int i = (blk - 6656) * 256 + tid;
    bqs[i] = bq[i] * 0.125f;                            // fold 1/8 into bq
  }
}

// ---------------- 128x128 GEMM core (BK=64, dbuf, global_load_lds) ----------------
// C[M,N] = A[M,K] @ B[N,K]^T + bias (+resid). A,B bf16. K=1024 fixed.
// omode 0: C[row*1024 + col]; omode 1: vt store C[(row>>10)<<20 | col<<10 | row&1023]
template <typename OutT>
static __device__ __forceinline__ void gemm_core(
    const short* __restrict__ A, const short* __restrict__ B,
    OutT* __restrict__ C, const float* __restrict__ bias,
    const float* __restrict__ resid, int bm, int bn, int omode,
    short (*As)[128 * 64], short (*Bs)[128 * 64]) {
  const int tid = threadIdx.x, lane = tid & 63, wave = tid >> 6;
  const int fr = lane & 15, khi = lane >> 4;
  const int wr = wave >> 1, wc = wave & 1;

  f32x4 acc[4][4];
#pragma unroll
  for (int m = 0; m < 4; ++m)
#pragma unroll
    for (int n = 0; n < 4; ++n) acc[m][n] = (f32x4){0.f, 0.f, 0.f, 0.f};

  auto stage = [&](int buf, int k0) {
#pragma unroll
    for (int it = 0; it < 4; ++it) {
      int l = it * 256 + tid;
      int r = l >> 3, c = (l & 7) ^ (r & 7);
      gld16(A + (long)(bm + r) * 1024 + k0 + c * 8, &As[buf][l * 8]);
      gld16(B + (long)(bn + r) * 1024 + k0 + c * 8, &Bs[buf][l * 8]);
    }
  };

  stage(0, 0);
  __syncthreads();
  int cur = 0;
  for (int k0 = 0; k0 < 1024; k0 += 64) {
    if (k0 < 960) stage(cur ^ 1, k0 + 64);
#pragma unroll
    for (int ks = 0; ks < 64; ks += 32) {
      const int cc = (ks >> 3) + khi;
      short8 af[4], bf[4];
#pragma unroll
      for (int m = 0; m < 4; ++m) {
        const int ar = wr * 64 + m * 16 + fr;
        af[m] = *(const short8*)&As[cur][ar * 64 + ((cc ^ (ar & 7)) * 8)];
      }
#pragma unroll
      for (int n = 0; n < 4; ++n) {
        const int br = wc * 64 + n * 16 + fr;
        bf[n] = *(const short8*)&Bs[cur][br * 64 + ((cc ^ (br & 7)) * 8)];
      }
#pragma unroll
      for (int m = 0; m < 4; ++m)
#pragma unroll
        for (int n = 0; n < 4; ++n)
          acc[m][n] = __builtin_amdgcn_mfma_f32_16x16x32_bf16(af[m], bf[n],
                                                              acc[m][n], 0, 0, 0);
    }
    __syncthreads();
    cur ^= 1;
  }

  const int col0 = lane & 15, row0 = (lane >> 4) * 4;
#pragma unroll
  for (int m = 0; m < 4; ++m) {
#pragma unroll
    for (int n = 0; n < 4; ++n) {
      const int gcol = bn + wc * 64 + n * 16 + col0;
      const float bi = bias[gcol];
#pragma unroll
      for (int i = 0; i < 4; ++i) {
        const int grow = bm + wr * 64 + m * 16 + row0 + i;
        float v = acc[m][n][i] + bi;
        if (resid) v += resid[(long)grow * 1024 + gcol];
        long addr;
        if (omode == 0)
          addr = (long)grow * 1024 + gcol;
        else
          addr = ((long)(grow >> 10) << 20) + ((long)gcol << 10) + (grow & 1023);
        if constexpr (sizeof(OutT) == 2)
          C[addr] = (OutT)f2bf(v);
        else
          C[addr] = v;
      }
    }
  }
}

// three projections in one launch: seg 0: qb, 1: kb, 2: vt
__global__ __launch_bounds__(256, 2) void proj_all(
    const short* __restrict__ Qb, const short* __restrict__ KVb,
    const short* __restrict__ Wqb, const short* __restrict__ Wkb,
    const short* __restrict__ Wvb,
    const float* __restrict__ bqs, const float* __restrict__ bk,
    const float* __restrict__ bv,
    short* __restrict__ qb, short* __restrict__ kb, short* __restrict__ vt) {
  __shared__ short As[2][128 * 64];
  __shared__ short Bs[2][128 * 64];
  int bid = blockIdx.x;
  int swz = (bid & 7) * 96 + (bid >> 3);     // 768 blocks, XCD-contiguous
  const int seg = swz >> 8, local = swz & 255;
  const int bm = (local >> 3) * 128, bn = (local & 7) * 128;
  if (seg == 0)
    gemm_core<short>(Qb, Wqb, qb, bqs, nullptr, bm, bn, 0, As, Bs);
  else if (seg == 1)
    gemm_core<short>(KVb, Wkb, kb, bk, nullptr, bm, bn, 0, As, Bs);
  else
    gemm_core<short>(KVb, Wvb, vt, bv, nullptr, bm, bn, 1, As, Bs);
}

// final GEMM: pre = at @ Wpb^T + bp + Q
__global__ __launch_bounds__(256, 2) void out_gemm(
    const short* __restrict__ at, const short* __restrict__ Wpb,
    const float* __restrict__ bp, const float* __restrict__ Q,
    float* __restrict__ pre) {
  __shared__ short As[2][128 * 64];
  __shared__ short Bs[2][128 * 64];
  int bid = blockIdx.x;
  int swz = (bid & 7) * 32 + (bid >> 3);     // 256 blocks
  const int bm = (swz >> 3) * 128, bn = (swz & 7) * 128;
  gemm_core<float>(at, Wpb, pre, bp, Q, bm, bn, 0, As, Bs);
}

// ---------------- fused attention (unchanged from R7) ----------------
__global__ __launch_bounds__(512, 6) void fused_attn(
    const short* __restrict__ qb,   // [4][1024][1024] bf16, feat = g*64+d (x1/8)
    const short* __restrict__ kb,   // [4][1024][1024] bf16, feat = g*64+d
    const short* __restrict__ vt,   // [4][1024][1024] bf16, vt[b][d*16+g][t]
    float* __restrict__ scores,     // [64][1024][1024] f32
    short* __restrict__ at) {       // [4][1024][1024] bf16, feat = g*64+d
  constexpr int LP = 72;
  __shared__ short Ks[2][64 * 64];  // 16 KB
  __shared__ short Vs[2][64 * 64];  // 16 KB
  __shared__ short Ps[128 * LP];    // 18 KB (wave-private 16-row slabs)

  int bid = blockIdx.x;
  bid = (bid & 7) * 64 + (bid >> 3);      // 8 z's per XCD
  const int z = bid >> 3, b = z >> 4, g = z & 15;
  const int q0 = (bid & 7) * 128;

  const int tid = threadIdx.x, lane = tid & 63, w = tid >> 6;
  const int fr = lane & 15, khi = lane >> 4;
  const long bqk = (long)b << 20;
  const int qr = q0 + w * 16;

  const short* qrow = qb + bqk + (long)(qr + fr) * 1024 + g * 64 + khi * 8;
  const short8 aq0 = *(const short8*)qrow;
  const short8 aq1 = *(const short8*)(qrow + 32);
  const short* kgp = kb + bqk + g * 64;
  const short* vgp = vt + bqk;

  const int srr = tid >> 3, ssc = ((tid & 7) ^ (srr & 7)) * 8;

  // ---- pass 1: exp-sums ----
  float s4[4] = {0.f, 0.f, 0.f, 0.f};
  gld16(kgp + (long)srr * 1024 + ssc, &Ks[0][tid * 8]);
  __syncthreads();
  int cur = 0;
  for (int t0 = 0; t0 < 1024; t0 += 64) {
    if (t0 < 960)
      gld16(kgp + (long)(t0 + 64 + srr) * 1024 + ssc, &Ks[cur ^ 1][tid * 8]);
    f32x4 sacc[4];
#pragma unroll
    for (int nf = 0; nf < 4; ++nf) sacc[nf] = (f32x4){0.f, 0.f, 0.f, 0.f};
#pragma unroll
    for (int nf = 0; nf < 4; ++nf) {
      const int r2 = nf * 16 + fr;
      short8 b0 = *(const short8*)&Ks[cur][r2 * 64 + (khi ^ (r2 & 7)) * 8];
      short8 b1 = *(const short8*)&Ks[cur][r2 * 64 + ((khi + 4) ^ (r2 & 7)) * 8];
      sacc[nf] = __builtin_amdgcn_mfma_f32_16x16x32_bf16(aq0, b0, sacc[nf], 0, 0, 0);
      sacc[nf] = __builtin_amdgcn_mfma_f32_16x16x32_bf16(aq1, b1, sacc[nf], 0, 0, 0);
    }
#pragma unroll
    for (int nf = 0; nf < 4; ++nf)
#pragma unroll
      for (int i = 0; i < 4; ++i) s4[i] += __expf(sacc[nf][i]);
    __syncthreads();
    cur ^= 1;
  }
#pragma unroll
  for (int i = 0; i < 4; ++i) {
    s4[i] += __shfl_xor(s4[i], 1);
    s4[i] += __shfl_xor(s4[i], 2);
    s4[i] += __shfl_xor(s4[i], 4);
    s4[i] += __shfl_xor(s4[i], 8);
  }
  float inv4[4];
#pragma unroll
  for (int i = 0; i < 4; ++i) inv4[i] = 1.f / s4[i];

  // ---- pass 2: recompute, P -> Ps, PV, coalesced score write ----
  f32x4 pacc[4];
#pragma unroll
  for (int nv = 0; nv < 4; ++nv) pacc[nv] = (f32x4){0.f, 0.f, 0.f, 0.f};

  gld16(kgp + (long)srr * 1024 + ssc, &Ks[0][tid * 8]);
  gld16(vgp + ((long)(srr * 16 + g) << 10) + ssc, &Vs[0][tid * 8]);
  __syncthreads();
  cur = 0;
  for (int t0 = 0; t0 < 1024; t0 += 64) {
    if (t0 < 960) {
      gld16(kgp + (long)(t0 + 64 + srr) * 1024 + ssc, &Ks[cur ^ 1][tid * 8]);
      gld16(vgp + ((long)(srr * 16 + g) << 10) + t0 + 64 + ssc, &Vs[cur ^ 1][tid * 8]);
    }
    f32x4 sacc[4];
#pragma unroll
    for (int nf = 0; nf < 4; ++nf) sacc[nf] = (f32x4){0.f, 0.f, 0.f, 0.f};
#pragma unroll
    for (int nf = 0; nf < 4; ++nf) {
      const int r2 = nf * 16 + fr;
      short8 b0 = *(const short8*)&Ks[cur][r2 * 64 + (khi ^ (r2 & 7)) * 8];
      short8 b1 = *(const short8*)&Ks[cur][r2 * 64 + ((khi + 4) ^ (r2 & 7)) * 8];
      sacc[nf] = __builtin_amdgcn_mfma_f32_16x16x32_bf16(aq0, b0, sacc[nf], 0, 0, 0);
      sacc[nf] = __builtin_amdgcn_mfma_f32_16x16x32_bf16(aq1, b1, sacc[nf], 0, 0, 0);
    }
#pragma unroll
    for (int nf = 0; nf < 4; ++nf)
#pragma unroll
      for (int i = 0; i < 4; ++i)
        Ps[(w * 16 + khi * 4 + i) * LP + nf * 16 + fr] =
            f2bf(__expf(sacc[nf][i]) * inv4[i]);

#pragma unroll
    for (int ks = 0; ks < 64; ks += 32) {
      const int cc = (ks >> 3) + khi;
      short8 ap = *(const short8*)&Ps[(w * 16 + fr) * LP + ks + khi * 8];
#pragma unroll
      for (int nv = 0; nv < 4; ++nv) {
        const int dr = nv * 16 + fr;
        short8 bvv = *(const short8*)&Vs[cur][dr * 64 + (cc ^ (dr & 7)) * 8];
        pacc[nv] = __builtin_amdgcn_mfma_f32_16x16x32_bf16(ap, bvv, pacc[nv], 0, 0, 0);
      }
    }

#pragma unroll
    for (int ri = 0; ri < 4; ++ri) {
      const int row = ri * 4 + khi;
      s16x4 pv4 = *(const s16x4*)&Ps[(w * 16 + row) * LP + fr * 4];
      f32x4 o;
      o[0] = bf2f(pv4[0]); o[1] = bf2f(pv4[1]);
      o[2] = bf2f(pv4[2]); o[3] = bf2f(pv4[3]);
      *(f32x4*)&scores[((long)z << 20) + ((long)(qr + row) << 10) + t0 + fr * 4] = o;
    }
    __syncthreads();
    cur ^= 1;
  }

#pragma unroll
  for (int nv = 0; nv < 4; ++nv)
#pragma unroll
    for (int i = 0; i < 4; ++i)
      at[bqk + ((long)(qr + khi * 4 + i) << 10) + g * 64 + nv * 16 + fr] =
          f2bf(pacc[nv][i]);
}

// one wave per 1024-elem row
__global__ __launch_bounds__(256) void layernorm_rows(const float* __restrict__ X,
                                                      const float* __restrict__ gamma,
                                                      const float* __restrict__ beta,
                                                      float* __restrict__ O) {
  const int row = blockIdx.x * 4 + (threadIdx.x >> 6);
  const int lane = threadIdx.x & 63;
  const float* x = X + (long)row * 1024 + lane * 4;
  f32x4 v[4];
  float s = 0.f, sq = 0.f;
#pragma unroll
  for (int j = 0; j < 4; ++j) {
    v[j] = *(const f32x4*)(x + j * 256);
#pragma unroll
    for (int e = 0; e < 4; ++e) {
      s += v[j][e];
      sq += v[j][e] * v[j][e];
    }
  }
#pragma unroll
  for (int off = 32; off; off >>= 1) {
    s += __shfl_xor(s, off);
    sq += __shfl_xor(sq, off);
  }
  const float mu = s * (1.f / 1024.f);
  const float var = sq * (1.f / 1024.f) - mu * mu;
  const float rstd = rsqrtf(var + 1e-5f);
  float* o = O + (long)row * 1024 + lane * 4;
#pragma unroll
  for (int j = 0; j < 4; ++j) {
    f32x4 g = *(const f32x4*)(gamma + lane * 4 + j * 256);
    f32x4 be = *(const f32x4*)(beta + lane * 4 + j * 256);
    f32x4 r;
#pragma unroll
    for (int e = 0; e < 4; ++e) r[e] = (v[j][e] - mu) * rstd * g[e] + be[e];
    *(f32x4*)(o + j * 256) = r;
  }
}

extern "C" void kernel_launch(void* const* d_in, const int* in_sizes, int n_in,
                              void* d_out, int out_size, void* d_ws, size_t ws_size,
                              hipStream_t stream) {
  const float* Q = (const float*)d_in[0];
  const float* KV = (const float*)d_in[1];
  const float* Wq = (const float*)d_in[2];
  const float* bq = (const float*)d_in[3];
  const float* Wk = (const float*)d_in[4];
  const float* bk = (const float*)d_in[5];
  const float* Wv = (const float*)d_in[6];
  const float* bv = (const float*)d_in[7];
  const float* Wp = (const float*)d_in[8];
  const float* bp = (const float*)d_in[9];
  const float* gamma = (const float*)d_in[10];
  const float* beta = (const float*)d_in[11];

  float* out = (float*)d_out;                       // [4M] f32
  float* scores = out + (long)4 * 1024 * 1024;      // [64M] f32

  char* ws = (char*)d_ws;
  short* Wqb = (short*)(ws);                        // 2MB each
  short* Wkb = (short*)(ws + (2L << 20));
  short* Wvb = (short*)(ws + (4L << 20));
  short* Wpb = (short*)(ws + (6L << 20));           // permuted columns
  short* qb  = (short*)(ws + (8L << 20));           // 8MB (pre-scaled by 1/8)
  short* kb  = (short*)(ws + (16L << 20));          // 8MB
  short* vt  = (short*)(ws + (24L << 20));          // 8MB
  short* at  = (short*)(ws + (32L << 20));          // 8MB, feat = g*64+d
  float* pre = (float*)(ws + (40L << 20));          // 16MB (written after attn)
  short* Qb  = (short*)(ws + (40L << 20));          // 8MB  (dead before pre)
  short* KVb = (short*)(ws + (48L << 20));          // 8MB  (dead before pre)
  float* bqs = (float*)(ws + (56L << 20));          // 4KB
  (void)ws_size; (void)in_sizes; (void)n_in; (void)out_size;

  // 1) all conversions, one launch
  prep<<<6660, 256, 0, stream>>>(Q, KV, Wq, Wk, Wv, Wp, bq,
                                 Qb, KVb, Wqb, Wkb, Wvb, Wpb, bqs);

  // 2) three projections, one launch
  proj_all<<<768, 256, 0, stream>>>(Qb, KVb, Wqb, Wkb, Wvb, bqs, bk, bv,
                                    qb, kb, vt);

  // 3) fused attention: scores (d_out) + at
  fused_attn<<<512, 512, 0, stream>>>(qb, kb, vt, scores, at);

  // 4) pre = at @ Wpb^T + bp + Q
  out_gemm<<<256, 256, 0, stream>>>(at, Wpb, bp, Q, pre);

  // 5) LayerNorm -> out
  layernorm_rows<<<1024, 256, 0, stream>>>(pre, gamma, beta, out);
}

// Round 9
// 178.325 us; speedup vs baseline: 2.1352x; 1.0051x over previous
//
#include <hip/hip_runtime.h>

typedef __attribute__((ext_vector_type(8))) short short8;
typedef __attribute__((ext_vector_type(4))) short s16x4;
typedef __attribute__((ext_vector_type(4))) float f32x4;

static __device__ __forceinline__ short f2bf(float x) {
  union { float f; unsigned u; } v; v.f = x;
  unsigned r = (v.u + 0x7fffu + ((v.u >> 16) & 1u)) >> 16;
  return (short)r;
}
static __device__ __forceinline__ float bf2f(short x) {
  union { unsigned u; float f; } v; v.u = ((unsigned)(unsigned short)x) << 16;
  return v.f;
}

// async 16B global -> LDS (dest: wave-uniform base + lane*16; src: per-lane)
static __device__ __forceinline__ void gld16(const short* g, short* l) {
  __builtin_amdgcn_global_load_lds(
      (const __attribute__((address_space(1))) unsigned*)g,
      (__attribute__((address_space(3))) unsigned*)l, 16, 0, 0);
}

// ---------------- prep: all conversions in one launch ----------------
static __device__ __forceinline__ void conv8(const float* __restrict__ src,
                                             short* __restrict__ dst, int i,
                                             float scale) {
  const f32x4* s = (const f32x4*)(src + (long)i * 8);
  f32x4 a = s[0], b = s[1];
  short8 o;
  o[0] = f2bf(a[0] * scale); o[1] = f2bf(a[1] * scale);
  o[2] = f2bf(a[2] * scale); o[3] = f2bf(a[3] * scale);
  o[4] = f2bf(b[0] * scale); o[5] = f2bf(b[1] * scale);
  o[6] = f2bf(b[2] * scale); o[7] = f2bf(b[3] * scale);
  *(short8*)(dst + (long)i * 8) = o;
}

__global__ __launch_bounds__(256) void prep(
    const float* __restrict__ Q, const float* __restrict__ KV,
    const float* __restrict__ Wq, const float* __restrict__ Wk,
    const float* __restrict__ Wv, const float* __restrict__ Wp,
    const float* __restrict__ bq,
    short* __restrict__ Qb, short* __restrict__ KVb,
    short* __restrict__ Wqb, short* __restrict__ Wkb,
    short* __restrict__ Wvb, short* __restrict__ Wpb,
    float* __restrict__ bqs) {
  const int blk = blockIdx.x, tid = threadIdx.x;
  if (blk < 2048) {
    conv8(Q, Qb, blk * 256 + tid, 1.f);
  } else if (blk < 4096) {
    conv8(KV, KVb, (blk - 2048) * 256 + tid, 1.f);
  } else if (blk < 4608) {
    conv8(Wq, Wqb, (blk - 4096) * 256 + tid, 0.125f);   // fold 1/8 into Wq
  } else if (blk < 5120) {
    conv8(Wk, Wkb, (blk - 4608) * 256 + tid, 1.f);
  } else if (blk < 5632) {
    conv8(Wv, Wvb, (blk - 5120) * 256 + tid, 1.f);
  } else if (blk < 6656) {
    // Wpb[o][g*64+d] = Wp[o][d*16+g]
    __shared__ float row[1024];
    const long o = blk - 5632;
    *(f32x4*)&row[tid * 4] = *(const f32x4*)(Wp + o * 1024 + tid * 4);
    __syncthreads();
    const int f0 = tid * 4;
    s16x4 t;
#pragma unroll
    for (int j = 0; j < 4; ++j) {
      int f = f0 + j;
      t[j] = f2bf(row[((f & 63) << 4) + (f >> 6)]);
    }
    *(s16x4*)(Wpb + o * 1024 + f0) = t;
  } else {
    int i = (blk - 6656) * 256 + tid;
    bqs[i] = bq[i] * 0.125f;                            // fold 1/8 into bq
  }
}

// ---------------- 128x128 GEMM core (BK=64, dbuf, global_load_lds) ----------------
template <typename OutT>
static __device__ __forceinline__ void gemm_core(
    const short* __restrict__ A, const short* __restrict__ B,
    OutT* __restrict__ C, const float* __restrict__ bias,
    const float* __restrict__ resid, int bm, int bn, int omode,
    short (*As)[128 * 64], short (*Bs)[128 * 64]) {
  const int tid = threadIdx.x, lane = tid & 63, wave = tid >> 6;
  const int fr = lane & 15, khi = lane >> 4;
  const int wr = wave >> 1, wc = wave & 1;

  f32x4 acc[4][4];
#pragma unroll
  for (int m = 0; m < 4; ++m)
#pragma unroll
    for (int n = 0; n < 4; ++n) acc[m][n] = (f32x4){0.f, 0.f, 0.f, 0.f};

  auto stage = [&](int buf, int k0) {
#pragma unroll
    for (int it = 0; it < 4; ++it) {
      int l = it * 256 + tid;
      int r = l >> 3, c = (l & 7) ^ (r & 7);
      gld16(A + (long)(bm + r) * 1024 + k0 + c * 8, &As[buf][l * 8]);
      gld16(B + (long)(bn + r) * 1024 + k0 + c * 8, &Bs[buf][l * 8]);
    }
  };

  stage(0, 0);
  __syncthreads();
  int cur = 0;
  for (int k0 = 0; k0 < 1024; k0 += 64) {
    if (k0 < 960) stage(cur ^ 1, k0 + 64);
#pragma unroll
    for (int ks = 0; ks < 64; ks += 32) {
      const int cc = (ks >> 3) + khi;
      short8 af[4], bf[4];
#pragma unroll
      for (int m = 0; m < 4; ++m) {
        const int ar = wr * 64 + m * 16 + fr;
        af[m] = *(const short8*)&As[cur][ar * 64 + ((cc ^ (ar & 7)) * 8)];
      }
#pragma unroll
      for (int n = 0; n < 4; ++n) {
        const int br = wc * 64 + n * 16 + fr;
        bf[n] = *(const short8*)&Bs[cur][br * 64 + ((cc ^ (br & 7)) * 8)];
      }
#pragma unroll
      for (int m = 0; m < 4; ++m)
#pragma unroll
        for (int n = 0; n < 4; ++n)
          acc[m][n] = __builtin_amdgcn_mfma_f32_16x16x32_bf16(af[m], bf[n],
                                                              acc[m][n], 0, 0, 0);
    }
    __syncthreads();
    cur ^= 1;
  }

  const int col0 = lane & 15, row0 = (lane >> 4) * 4;
#pragma unroll
  for (int m = 0; m < 4; ++m) {
#pragma unroll
    for (int n = 0; n < 4; ++n) {
      const int gcol = bn + wc * 64 + n * 16 + col0;
      const float bi = bias[gcol];
#pragma unroll
      for (int i = 0; i < 4; ++i) {
        const int grow = bm + wr * 64 + m * 16 + row0 + i;
        float v = acc[m][n][i] + bi;
        if (resid) v += resid[(long)grow * 1024 + gcol];
        long addr;
        if (omode == 0)
          addr = (long)grow * 1024 + gcol;
        else
          addr = ((long)(grow >> 10) << 20) + ((long)gcol << 10) + (grow & 1023);
        if constexpr (sizeof(OutT) == 2)
          C[addr] = (OutT)f2bf(v);
        else
          C[addr] = v;
      }
    }
  }
}

// three projections in one launch: seg 0: qb, 1: kb, 2: vt
__global__ __launch_bounds__(256, 2) void proj_all(
    const short* __restrict__ Qb, const short* __restrict__ KVb,
    const short* __restrict__ Wqb, const short* __restrict__ Wkb,
    const short* __restrict__ Wvb,
    const float* __restrict__ bqs, const float* __restrict__ bk,
    const float* __restrict__ bv,
    short* __restrict__ qb, short* __restrict__ kb, short* __restrict__ vt) {
  __shared__ short As[2][128 * 64];
  __shared__ short Bs[2][128 * 64];
  int bid = blockIdx.x;
  int swz = (bid & 7) * 96 + (bid >> 3);     // 768 blocks, XCD-contiguous
  const int seg = swz >> 8, local = swz & 255;
  const int bm = (local >> 3) * 128, bn = (local & 7) * 128;
  if (seg == 0)
    gemm_core<short>(Qb, Wqb, qb, bqs, nullptr, bm, bn, 0, As, Bs);
  else if (seg == 1)
    gemm_core<short>(KVb, Wkb, kb, bk, nullptr, bm, bn, 0, As, Bs);
  else
    gemm_core<short>(KVb, Wvb, vt, bv, nullptr, bm, bn, 1, As, Bs);
}

// final GEMM: pre = at @ Wpb^T + bp + Q
__global__ __launch_bounds__(256, 2) void out_gemm(
    const short* __restrict__ at, const short* __restrict__ Wpb,
    const float* __restrict__ bp, const float* __restrict__ Q,
    float* __restrict__ pre) {
  __shared__ short As[2][128 * 64];
  __shared__ short Bs[2][128 * 64];
  int bid = blockIdx.x;
  int swz = (bid & 7) * 32 + (bid >> 3);     // 256 blocks
  const int bm = (swz >> 3) * 128, bn = (swz & 7) * 128;
  gemm_core<float>(at, Wpb, pre, bp, Q, bm, bn, 0, As, Bs);
}

// ---------------- fused attention v9: 4 waves x 32 q-rows ----------------
// Block = 256 thr (4 waves) per (z, 128 q-rows); wave owns 32 q-rows (2 sub-tiles
// of 16) x all keys -> each K/V fragment feeds 2 MFMAs. KT=64, dbuf staging,
// sum-only softmax, coalesced nontemporal score writes. LDS 50.4 KB, 3 blk/CU.
__global__ __launch_bounds__(256, 3) void fused_attn(
    const short* __restrict__ qb,   // [4][1024][1024] bf16, feat = g*64+d (x1/8)
    const short* __restrict__ kb,   // [4][1024][1024] bf16, feat = g*64+d
    const short* __restrict__ vt,   // [4][1024][1024] bf16, vt[b][d*16+g][t]
    float* __restrict__ scores,     // [64][1024][1024] f32
    short* __restrict__ at) {       // [4][1024][1024] bf16, feat = g*64+d
  constexpr int LP = 72;
  __shared__ short Ks[2][64 * 64];  // 16 KB
  __shared__ short Vs[2][64 * 64];  // 16 KB
  __shared__ short Ps[128 * LP];    // 18.4 KB (wave-private 32-row slabs)

  int bid = blockIdx.x;
  bid = (bid & 7) * 64 + (bid >> 3);      // 8 z's per XCD
  const int z = bid >> 3, b = z >> 4, g = z & 15;
  const int q0 = (bid & 7) * 128;

  const int tid = threadIdx.x, lane = tid & 63, w = tid >> 6;
  const int fr = lane & 15, khi = lane >> 4;
  const long bqk = (long)b << 20;
  const int qr = q0 + w * 32;             // wave's first q row (32 rows)

  // Q fragments: 2 sub-tiles x 2 k-chunks
  short8 aq[4];
#pragma unroll
  for (int sub = 0; sub < 2; ++sub) {
    const short* qrow = qb + bqk + (long)(qr + sub * 16 + fr) * 1024 + g * 64 + khi * 8;
    aq[sub * 2] = *(const short8*)qrow;
    aq[sub * 2 + 1] = *(const short8*)(qrow + 32);
  }
  const short* kgp = kb + bqk + g * 64;
  const short* vgp = vt + bqk;

  // staging: 512 chunks of 16B per 64x64 tile, 256 thr -> 2 chunks/thread
  auto stageK = [&](int buf, int t0) {
#pragma unroll
    for (int it = 0; it < 2; ++it) {
      int l = it * 256 + tid;
      int r = l >> 3, c = (l & 7) ^ (r & 7);
      gld16(kgp + (long)(t0 + r) * 1024 + c * 8, &Ks[buf][l * 8]);
    }
  };
  auto stageV = [&](int buf, int t0) {
#pragma unroll
    for (int it = 0; it < 2; ++it) {
      int l = it * 256 + tid;
      int r = l >> 3, c = (l & 7) ^ (r & 7);
      gld16(vgp + ((long)(r * 16 + g) << 10) + t0 + c * 8, &Vs[buf][l * 8]);
    }
  };

  // ---- pass 1: exp-sums ----
  float s4[2][4] = {{0.f, 0.f, 0.f, 0.f}, {0.f, 0.f, 0.f, 0.f}};
  stageK(0, 0);
  __syncthreads();
  int cur = 0;
  for (int t0 = 0; t0 < 1024; t0 += 64) {
    if (t0 < 960) stageK(cur ^ 1, t0 + 64);
#pragma unroll
    for (int nf = 0; nf < 4; ++nf) {
      const int r2 = nf * 16 + fr;
      short8 b0 = *(const short8*)&Ks[cur][r2 * 64 + (khi ^ (r2 & 7)) * 8];
      short8 b1 = *(const short8*)&Ks[cur][r2 * 64 + ((khi + 4) ^ (r2 & 7)) * 8];
#pragma unroll
      for (int sub = 0; sub < 2; ++sub) {
        f32x4 sacc = (f32x4){0.f, 0.f, 0.f, 0.f};
        sacc = __builtin_amdgcn_mfma_f32_16x16x32_bf16(aq[sub * 2], b0, sacc, 0, 0, 0);
        sacc = __builtin_amdgcn_mfma_f32_16x16x32_bf16(aq[sub * 2 + 1], b1, sacc, 0, 0, 0);
#pragma unroll
        for (int i = 0; i < 4; ++i) s4[sub][i] += __expf(sacc[i]);
      }
    }
    __syncthreads();
    cur ^= 1;
  }
  float inv4[2][4];
#pragma unroll
  for (int sub = 0; sub < 2; ++sub)
#pragma unroll
    for (int i = 0; i < 4; ++i) {
      float s = s4[sub][i];
      s += __shfl_xor(s, 1);
      s += __shfl_xor(s, 2);
      s += __shfl_xor(s, 4);
      s += __shfl_xor(s, 8);
      inv4[sub][i] = 1.f / s;
    }

  // ---- pass 2: recompute, P -> Ps, PV, coalesced nontemporal score write ----
  f32x4 pacc[2][4];
#pragma unroll
  for (int sub = 0; sub < 2; ++sub)
#pragma unroll
    for (int nv = 0; nv < 4; ++nv) pacc[sub][nv] = (f32x4){0.f, 0.f, 0.f, 0.f};

  stageK(0, 0);
  stageV(0, 0);
  __syncthreads();
  cur = 0;
  for (int t0 = 0; t0 < 1024; t0 += 64) {
    if (t0 < 960) {
      stageK(cur ^ 1, t0 + 64);
      stageV(cur ^ 1, t0 + 64);
    }
#pragma unroll
    for (int nf = 0; nf < 4; ++nf) {
      const int r2 = nf * 16 + fr;
      short8 b0 = *(const short8*)&Ks[cur][r2 * 64 + (khi ^ (r2 & 7)) * 8];
      short8 b1 = *(const short8*)&Ks[cur][r2 * 64 + ((khi + 4) ^ (r2 & 7)) * 8];
#pragma unroll
      for (int sub = 0; sub < 2; ++sub) {
        f32x4 sacc = (f32x4){0.f, 0.f, 0.f, 0.f};
        sacc = __builtin_amdgcn_mfma_f32_16x16x32_bf16(aq[sub * 2], b0, sacc, 0, 0, 0);
        sacc = __builtin_amdgcn_mfma_f32_16x16x32_bf16(aq[sub * 2 + 1], b1, sacc, 0, 0, 0);
#pragma unroll
        for (int i = 0; i < 4; ++i)
          Ps[(w * 32 + sub * 16 + khi * 4 + i) * LP + nf * 16 + fr] =
              f2bf(__expf(sacc[i]) * inv4[sub][i]);
      }
    }

    // PV: V fragments shared across the two sub-tiles
#pragma unroll
    for (int ks = 0; ks < 64; ks += 32) {
      const int cc = (ks >> 3) + khi;
      short8 ap[2];
#pragma unroll
      for (int sub = 0; sub < 2; ++sub)
        ap[sub] = *(const short8*)&Ps[(w * 32 + sub * 16 + fr) * LP + ks + khi * 8];
#pragma unroll
      for (int nv = 0; nv < 4; ++nv) {
        const int dr = nv * 16 + fr;
        short8 bvv = *(const short8*)&Vs[cur][dr * 64 + (cc ^ (dr & 7)) * 8];
#pragma unroll
        for (int sub = 0; sub < 2; ++sub)
          pacc[sub][nv] =
              __builtin_amdgcn_mfma_f32_16x16x32_bf16(ap[sub], bvv, pacc[sub][nv], 0, 0, 0);
      }
    }

    // coalesced score write: 32 rows x 256B, nontemporal
#pragma unroll
    for (int ri = 0; ri < 8; ++ri) {
      const int row = ri * 4 + khi;
      s16x4 pv4 = *(const s16x4*)&Ps[(w * 32 + row) * LP + fr * 4];
      f32x4 o;
      o[0] = bf2f(pv4[0]); o[1] = bf2f(pv4[1]);
      o[2] = bf2f(pv4[2]); o[3] = bf2f(pv4[3]);
      __builtin_nontemporal_store(
          o, (f32x4*)&scores[((long)z << 20) + ((long)(qr + row) << 10) + t0 + fr * 4]);
    }
    __syncthreads();
    cur ^= 1;
  }

  // at[b][q][g*64 + d]
#pragma unroll
  for (int sub = 0; sub < 2; ++sub)
#pragma unroll
    for (int nv = 0; nv < 4; ++nv)
#pragma unroll
      for (int i = 0; i < 4; ++i)
        at[bqk + ((long)(qr + sub * 16 + khi * 4 + i) << 10) + g * 64 + nv * 16 + fr] =
            f2bf(pacc[sub][nv][i]);
}

// one wave per 1024-elem row
__global__ __launch_bounds__(256) void layernorm_rows(const float* __restrict__ X,
                                                      const float* __restrict__ gamma,
                                                      const float* __restrict__ beta,
                                                      float* __restrict__ O) {
  const int row = blockIdx.x * 4 + (threadIdx.x >> 6);
  const int lane = threadIdx.x & 63;
  const float* x = X + (long)row * 1024 + lane * 4;
  f32x4 v[4];
  float s = 0.f, sq = 0.f;
#pragma unroll
  for (int j = 0; j < 4; ++j) {
    v[j] = *(const f32x4*)(x + j * 256);
#pragma unroll
    for (int e = 0; e < 4; ++e) {
      s += v[j][e];
      sq += v[j][e] * v[j][e];
    }
  }
#pragma unroll
  for (int off = 32; off; off >>= 1) {
    s += __shfl_xor(s, off);
    sq += __shfl_xor(sq, off);
  }
  const float mu = s * (1.f / 1024.f);
  const float var = sq * (1.f / 1024.f) - mu * mu;
  const float rstd = rsqrtf(var + 1e-5f);
  float* o = O + (long)row * 1024 + lane * 4;
#pragma unroll
  for (int j = 0; j < 4; ++j) {
    f32x4 g = *(const f32x4*)(gamma + lane * 4 + j * 256);
    f32x4 be = *(const f32x4*)(beta + lane * 4 + j * 256);
    f32x4 r;
#pragma unroll
    for (int e = 0; e < 4; ++e) r[e] = (v[j][e] - mu) * rstd * g[e] + be[e];
    *(f32x4*)(o + j * 256) = r;
  }
}

extern "C" void kernel_launch(void* const* d_in, const int* in_sizes, int n_in,
                              void* d_out, int out_size, void* d_ws, size_t ws_size,
                              hipStream_t stream) {
  const float* Q = (const float*)d_in[0];
  const float* KV = (const float*)d_in[1];
  const float* Wq = (const float*)d_in[2];
  const float* bq = (const float*)d_in[3];
  const float* Wk = (const float*)d_in[4];
  const float* bk = (const float*)d_in[5];
  const float* Wv = (const float*)d_in[6];
  const float* bv = (const float*)d_in[7];
  const float* Wp = (const float*)d_in[8];
  const float* bp = (const float*)d_in[9];
  const float* gamma = (const float*)d_in[10];
  const float* beta = (const float*)d_in[11];

  float* out = (float*)d_out;                       // [4M] f32
  float* scores = out + (long)4 * 1024 * 1024;      // [64M] f32

  char* ws = (char*)d_ws;
  short* Wqb = (short*)(ws);                        // 2MB each
  short* Wkb = (short*)(ws + (2L << 20));
  short* Wvb = (short*)(ws + (4L << 20));
  short* Wpb = (short*)(ws + (6L << 20));           // permuted columns
  short* qb  = (short*)(ws + (8L << 20));           // 8MB (pre-scaled by 1/8)
  short* kb  = (short*)(ws + (16L << 20));          // 8MB
  short* vt  = (short*)(ws + (24L << 20));          // 8MB
  short* at  = (short*)(ws + (32L << 20));          // 8MB, feat = g*64+d
  float* pre = (float*)(ws + (40L << 20));          // 16MB (written after attn)
  short* Qb  = (short*)(ws + (40L << 20));          // 8MB  (dead before pre)
  short* KVb = (short*)(ws + (48L << 20));          // 8MB  (dead before pre)
  float* bqs = (float*)(ws + (56L << 20));          // 4KB
  (void)ws_size; (void)in_sizes; (void)n_in; (void)out_size;

  // 1) all conversions, one launch
  prep<<<6660, 256, 0, stream>>>(Q, KV, Wq, Wk, Wv, Wp, bq,
                                 Qb, KVb, Wqb, Wkb, Wvb, Wpb, bqs);

  // 2) three projections, one launch
  proj_all<<<768, 256, 0, stream>>>(Qb, KVb, Wqb, Wkb, Wvb, bqs, bk, bv,
                                    qb, kb, vt);

  // 3) fused attention: scores (d_out) + at
  fused_attn<<<512, 256, 0, stream>>>(qb, kb, vt, scores, at);

  // 4) pre = at @ Wpb^T + bp + Q
  out_gemm<<<256, 256, 0, stream>>>(at, Wpb, bp, Q, pre);

  // 5) LayerNorm -> out
  layernorm_rows<<<1024, 256, 0, stream>>>(pre, gamma, beta, out);
}

// Round 10
// 175.642 us; speedup vs baseline: 2.1678x; 1.0153x over previous
//
#include <hip/hip_runtime.h>

typedef __attribute__((ext_vector_type(8))) short short8;
typedef __attribute__((ext_vector_type(4))) short s16x4;
typedef __attribute__((ext_vector_type(4))) float f32x4;
typedef __attribute__((ext_vector_type(2))) unsigned u32x2;

static __device__ __forceinline__ short f2bf(float x) {
  union { float f; unsigned u; } v; v.f = x;
  unsigned r = (v.u + 0x7fffu + ((v.u >> 16) & 1u)) >> 16;
  return (short)r;
}
// packed f32x2 -> bf16x2 (RNE), 1 VALU op
static __device__ __forceinline__ unsigned cvtpk(float lo, float hi) {
  unsigned r;
  asm("v_cvt_pk_bf16_f32 %0, %1, %2" : "=v"(r) : "v"(lo), "v"(hi));
  return r;
}

// async 16B global -> LDS (dest: wave-uniform base + lane*16; src: per-lane)
static __device__ __forceinline__ void gld16(const short* g, short* l) {
  __builtin_amdgcn_global_load_lds(
      (const __attribute__((address_space(1))) unsigned*)g,
      (__attribute__((address_space(3))) unsigned*)l, 16, 0, 0);
}

// ---------------- prep: all conversions in one launch ----------------
static __device__ __forceinline__ void conv8(const float* __restrict__ src,
                                             short* __restrict__ dst, int i,
                                             float scale) {
  const f32x4* s = (const f32x4*)(src + (long)i * 8);
  f32x4 a = s[0], b = s[1];
  short8 o;
  o[0] = f2bf(a[0] * scale); o[1] = f2bf(a[1] * scale);
  o[2] = f2bf(a[2] * scale); o[3] = f2bf(a[3] * scale);
  o[4] = f2bf(b[0] * scale); o[5] = f2bf(b[1] * scale);
  o[6] = f2bf(b[2] * scale); o[7] = f2bf(b[3] * scale);
  *(short8*)(dst + (long)i * 8) = o;
}

__global__ __launch_bounds__(256) void prep(
    const float* __restrict__ Q, const float* __restrict__ KV,
    const float* __restrict__ Wq, const float* __restrict__ Wk,
    const float* __restrict__ Wv, const float* __restrict__ Wp,
    const float* __restrict__ bq,
    short* __restrict__ Qb, short* __restrict__ KVb,
    short* __restrict__ Wqb, short* __restrict__ Wkb,
    short* __restrict__ Wvb, short* __restrict__ Wpb,
    float* __restrict__ bqs) {
  const int blk = blockIdx.x, tid = threadIdx.x;
  if (blk < 2048) {
    conv8(Q, Qb, blk * 256 + tid, 1.f);
  } else if (blk < 4096) {
    conv8(KV, KVb, (blk - 2048) * 256 + tid, 1.f);
  } else if (blk < 4608) {
    conv8(Wq, Wqb, (blk - 4096) * 256 + tid, 0.125f);   // fold 1/8 into Wq
  } else if (blk < 5120) {
    conv8(Wk, Wkb, (blk - 4608) * 256 + tid, 1.f);
  } else if (blk < 5632) {
    conv8(Wv, Wvb, (blk - 5120) * 256 + tid, 1.f);
  } else if (blk < 6656) {
    // Wpb[o][g*64+d] = Wp[o][d*16+g]
    __shared__ float row[1024];
    const long o = blk - 5632;
    *(f32x4*)&row[tid * 4] = *(const f32x4*)(Wp + o * 1024 + tid * 4);
    __syncthreads();
    const int f0 = tid * 4;
    s16x4 t;
#pragma unroll
    for (int j = 0; j < 4; ++j) {
      int f = f0 + j;
      t[j] = f2bf(row[((f & 63) << 4) + (f >> 6)]);
    }
    *(s16x4*)(Wpb + o * 1024 + f0) = t;
  } else {
    int i = (blk - 6656) * 256 + tid;
    bqs[i] = bq[i] * 0.125f;                            // fold 1/8 into bq
  }
}

// ---------------- 128x128 GEMM core (BK=64, dbuf, global_load_lds) ----------------
template <typename OutT>
static __device__ __forceinline__ void gemm_core(
    const short* __restrict__ A, const short* __restrict__ B,
    OutT* __restrict__ C, const float* __restrict__ bias,
    const float* __restrict__ resid, int bm, int bn, int omode,
    short (*As)[128 * 64], short (*Bs)[128 * 64]) {
  const int tid = threadIdx.x, lane = tid & 63, wave = tid >> 6;
  const int fr = lane & 15, khi = lane >> 4;
  const int wr = wave >> 1, wc = wave & 1;

  f32x4 acc[4][4];
#pragma unroll
  for (int m = 0; m < 4; ++m)
#pragma unroll
    for (int n = 0; n < 4; ++n) acc[m][n] = (f32x4){0.f, 0.f, 0.f, 0.f};

  auto stage = [&](int buf, int k0) {
#pragma unroll
    for (int it = 0; it < 4; ++it) {
      int l = it * 256 + tid;
      int r = l >> 3, c = (l & 7) ^ (r & 7);
      gld16(A + (long)(bm + r) * 1024 + k0 + c * 8, &As[buf][l * 8]);
      gld16(B + (long)(bn + r) * 1024 + k0 + c * 8, &Bs[buf][l * 8]);
    }
  };

  stage(0, 0);
  __syncthreads();
  int cur = 0;
  for (int k0 = 0; k0 < 1024; k0 += 64) {
    if (k0 < 960) stage(cur ^ 1, k0 + 64);
#pragma unroll
    for (int ks = 0; ks < 64; ks += 32) {
      const int cc = (ks >> 3) + khi;
      short8 af[4], bf[4];
#pragma unroll
      for (int m = 0; m < 4; ++m) {
        const int ar = wr * 64 + m * 16 + fr;
        af[m] = *(const short8*)&As[cur][ar * 64 + ((cc ^ (ar & 7)) * 8)];
      }
#pragma unroll
      for (int n = 0; n < 4; ++n) {
        const int br = wc * 64 + n * 16 + fr;
        bf[n] = *(const short8*)&Bs[cur][br * 64 + ((cc ^ (br & 7)) * 8)];
      }
#pragma unroll
      for (int m = 0; m < 4; ++m)
#pragma unroll
        for (int n = 0; n < 4; ++n)
          acc[m][n] = __builtin_amdgcn_mfma_f32_16x16x32_bf16(af[m], bf[n],
                                                              acc[m][n], 0, 0, 0);
    }
    __syncthreads();
    cur ^= 1;
  }

  const int col0 = lane & 15, row0 = (lane >> 4) * 4;
#pragma unroll
  for (int m = 0; m < 4; ++m) {
#pragma unroll
    for (int n = 0; n < 4; ++n) {
      const int gcol = bn + wc * 64 + n * 16 + col0;
      const float bi = bias[gcol];
#pragma unroll
      for (int i = 0; i < 4; ++i) {
        const int grow = bm + wr * 64 + m * 16 + row0 + i;
        float v = acc[m][n][i] + bi;
        if (resid) v += resid[(long)grow * 1024 + gcol];
        long addr;
        if (omode == 0)
          addr = (long)grow * 1024 + gcol;
        else
          addr = ((long)(grow >> 10) << 20) + ((long)gcol << 10) + (grow & 1023);
        if constexpr (sizeof(OutT) == 2)
          C[addr] = (OutT)f2bf(v);
        else
          C[addr] = v;
      }
    }
  }
}

// three projections in one launch: seg 0: qb, 1: kb, 2: vt
__global__ __launch_bounds__(256, 2) void proj_all(
    const short* __restrict__ Qb, const short* __restrict__ KVb,
    const short* __restrict__ Wqb, const short* __restrict__ Wkb,
    const short* __restrict__ Wvb,
    const float* __restrict__ bqs, const float* __restrict__ bk,
    const float* __restrict__ bv,
    short* __restrict__ qb, short* __restrict__ kb, short* __restrict__ vt) {
  __shared__ short As[2][128 * 64];
  __shared__ short Bs[2][128 * 64];
  int bid = blockIdx.x;
  int swz = (bid & 7) * 96 + (bid >> 3);     // 768 blocks, XCD-contiguous
  const int seg = swz >> 8, local = swz & 255;
  const int bm = (local >> 3) * 128, bn = (local & 7) * 128;
  if (seg == 0)
    gemm_core<short>(Qb, Wqb, qb, bqs, nullptr, bm, bn, 0, As, Bs);
  else if (seg == 1)
    gemm_core<short>(KVb, Wkb, kb, bk, nullptr, bm, bn, 0, As, Bs);
  else
    gemm_core<short>(KVb, Wvb, vt, bv, nullptr, bm, bn, 1, As, Bs);
}

// final GEMM: pre = at @ Wpb^T + bp + Q
__global__ __launch_bounds__(256, 2) void out_gemm(
    const short* __restrict__ at, const short* __restrict__ Wpb,
    const float* __restrict__ bp, const float* __restrict__ Q,
    float* __restrict__ pre) {
  __shared__ short As[2][128 * 64];
  __shared__ short Bs[2][128 * 64];
  int bid = blockIdx.x;
  int swz = (bid & 7) * 32 + (bid >> 3);     // 256 blocks
  const int bm = (swz >> 3) * 128, bn = (swz & 7) * 128;
  gemm_core<float>(at, Wpb, pre, bp, Q, bm, bn, 0, As, Bs);
}

// ---------------- fused attention v10 ----------------
// 4 waves x 32 q-rows; K-feed permutation r2 = fr*4+nf so each lane's 4 sacc
// values are CONTIGUOUS keys fr*4+{0..3}: scores stored straight from registers
// (f32x4 NT), Ps packed via v_cvt_pk_bf16_f32 + ds_write_b64.
__global__ __launch_bounds__(256, 3) void fused_attn(
    const short* __restrict__ qb,   // [4][1024][1024] bf16, feat = g*64+d (x1/8)
    const short* __restrict__ kb,   // [4][1024][1024] bf16, feat = g*64+d
    const short* __restrict__ vt,   // [4][1024][1024] bf16, vt[b][d*16+g][t]
    float* __restrict__ scores,     // [64][1024][1024] f32
    short* __restrict__ at) {       // [4][1024][1024] bf16, feat = g*64+d
  constexpr int LP = 72;
  __shared__ short Ks[2][64 * 64];  // 16 KB  (XOR key = (row>>2)&7)
  __shared__ short Vs[2][64 * 64];  // 16 KB  (XOR key = row&7)
  __shared__ short Ps[128 * LP];    // 18.4 KB (wave-private 32-row slabs)

  int bid = blockIdx.x;
  bid = (bid & 7) * 64 + (bid >> 3);      // 8 z's per XCD
  const int z = bid >> 3, b = z >> 4, g = z & 15;
  const int q0 = (bid & 7) * 128;

  const int tid = threadIdx.x, lane = tid & 63, w = tid >> 6;
  const int fr = lane & 15, khi = lane >> 4;
  const long bqk = (long)b << 20;
  const int qr = q0 + w * 32;             // wave's first q row (32 rows)

  // Q fragments: 2 sub-tiles x 2 k-chunks
  short8 aq[4];
#pragma unroll
  for (int sub = 0; sub < 2; ++sub) {
    const short* qrow = qb + bqk + (long)(qr + sub * 16 + fr) * 1024 + g * 64 + khi * 8;
    aq[sub * 2] = *(const short8*)qrow;
    aq[sub * 2 + 1] = *(const short8*)(qrow + 32);
  }
  const short* kgp = kb + bqk + g * 64;
  const short* vgp = vt + bqk;

  // K staging: XOR key (row>>2)&7 = (l>>5)&7; V staging: XOR key row&7
  auto stageK = [&](int buf, int t0) {
#pragma unroll
    for (int it = 0; it < 2; ++it) {
      int l = it * 256 + tid;
      int r = l >> 3, c = (l & 7) ^ ((l >> 5) & 7);
      gld16(kgp + (long)(t0 + r) * 1024 + c * 8, &Ks[buf][l * 8]);
    }
  };
  auto stageV = [&](int buf, int t0) {
#pragma unroll
    for (int it = 0; it < 2; ++it) {
      int l = it * 256 + tid;
      int r = l >> 3, c = (l & 7) ^ (r & 7);
      gld16(vgp + ((long)(r * 16 + g) << 10) + t0 + c * 8, &Vs[buf][l * 8]);
    }
  };

  const int xk = fr & 7;                  // Ks read XOR key: (r2>>2)&7 with r2=fr*4+nf

  // ---- pass 1: exp-sums ----
  float s4[2][4] = {{0.f, 0.f, 0.f, 0.f}, {0.f, 0.f, 0.f, 0.f}};
  stageK(0, 0);
  __syncthreads();
  int cur = 0;
  for (int t0 = 0; t0 < 1024; t0 += 64) {
    if (t0 < 960) stageK(cur ^ 1, t0 + 64);
    f32x4 sacc[2][4];
#pragma unroll
    for (int sub = 0; sub < 2; ++sub)
#pragma unroll
      for (int nf = 0; nf < 4; ++nf) sacc[sub][nf] = (f32x4){0.f, 0.f, 0.f, 0.f};
#pragma unroll
    for (int nf = 0; nf < 4; ++nf) {
      const int r2 = fr * 4 + nf;
      short8 b0 = *(const short8*)&Ks[cur][r2 * 64 + ((khi ^ xk) * 8)];
      short8 b1 = *(const short8*)&Ks[cur][r2 * 64 + (((khi + 4) ^ xk) * 8)];
#pragma unroll
      for (int sub = 0; sub < 2; ++sub) {
        sacc[sub][nf] =
            __builtin_amdgcn_mfma_f32_16x16x32_bf16(aq[sub * 2], b0, sacc[sub][nf], 0, 0, 0);
        sacc[sub][nf] =
            __builtin_amdgcn_mfma_f32_16x16x32_bf16(aq[sub * 2 + 1], b1, sacc[sub][nf], 0, 0, 0);
      }
    }
#pragma unroll
    for (int sub = 0; sub < 2; ++sub)
#pragma unroll
      for (int nf = 0; nf < 4; ++nf)
#pragma unroll
        for (int i = 0; i < 4; ++i) s4[sub][i] += __expf(sacc[sub][nf][i]);
    __syncthreads();
    cur ^= 1;
  }
  float inv4[2][4];
#pragma unroll
  for (int sub = 0; sub < 2; ++sub)
#pragma unroll
    for (int i = 0; i < 4; ++i) {
      float s = s4[sub][i];
      s += __shfl_xor(s, 1);
      s += __shfl_xor(s, 2);
      s += __shfl_xor(s, 4);
      s += __shfl_xor(s, 8);
      inv4[sub][i] = 1.f / s;
    }

  // ---- pass 2: recompute, direct score store, packed Ps, PV ----
  f32x4 pacc[2][4];
#pragma unroll
  for (int sub = 0; sub < 2; ++sub)
#pragma unroll
    for (int nv = 0; nv < 4; ++nv) pacc[sub][nv] = (f32x4){0.f, 0.f, 0.f, 0.f};

  stageK(0, 0);
  stageV(0, 0);
  __syncthreads();
  cur = 0;
  for (int t0 = 0; t0 < 1024; t0 += 64) {
    if (t0 < 960) {
      stageK(cur ^ 1, t0 + 64);
      stageV(cur ^ 1, t0 + 64);
    }
    f32x4 sacc[2][4];
#pragma unroll
    for (int sub = 0; sub < 2; ++sub)
#pragma unroll
      for (int nf = 0; nf < 4; ++nf) sacc[sub][nf] = (f32x4){0.f, 0.f, 0.f, 0.f};
#pragma unroll
    for (int nf = 0; nf < 4; ++nf) {
      const int r2 = fr * 4 + nf;
      short8 b0 = *(const short8*)&Ks[cur][r2 * 64 + ((khi ^ xk) * 8)];
      short8 b1 = *(const short8*)&Ks[cur][r2 * 64 + (((khi + 4) ^ xk) * 8)];
#pragma unroll
      for (int sub = 0; sub < 2; ++sub) {
        sacc[sub][nf] =
            __builtin_amdgcn_mfma_f32_16x16x32_bf16(aq[sub * 2], b0, sacc[sub][nf], 0, 0, 0);
        sacc[sub][nf] =
            __builtin_amdgcn_mfma_f32_16x16x32_bf16(aq[sub * 2 + 1], b1, sacc[sub][nf], 0, 0, 0);
      }
    }
    // epilogue: lane holds keys fr*4+{0..3} for rows khi*4+i (+sub*16)
#pragma unroll
    for (int sub = 0; sub < 2; ++sub) {
#pragma unroll
      for (int i = 0; i < 4; ++i) {
        f32x4 o;
#pragma unroll
        for (int nf = 0; nf < 4; ++nf)
          o[nf] = __expf(sacc[sub][nf][i]) * inv4[sub][i];
        const int row = sub * 16 + khi * 4 + i;
        __builtin_nontemporal_store(
            o, (f32x4*)&scores[((long)z << 20) + ((long)(qr + row) << 10) + t0 + fr * 4]);
        u32x2 pp;
        pp[0] = cvtpk(o[0], o[1]);
        pp[1] = cvtpk(o[2], o[3]);
        *(u32x2*)&Ps[(w * 32 + row) * LP + fr * 4] = pp;
      }
    }

    // PV: V fragments shared across the two sub-tiles (keys in natural order)
#pragma unroll
    for (int ks = 0; ks < 64; ks += 32) {
      const int cc = (ks >> 3) + khi;
      short8 ap[2];
#pragma unroll
      for (int sub = 0; sub < 2; ++sub)
        ap[sub] = *(const short8*)&Ps[(w * 32 + sub * 16 + fr) * LP + ks + khi * 8];
#pragma unroll
      for (int nv = 0; nv < 4; ++nv) {
        const int dr = nv * 16 + fr;
        short8 bvv = *(const short8*)&Vs[cur][dr * 64 + ((cc ^ (dr & 7)) * 8)];
#pragma unroll
        for (int sub = 0; sub < 2; ++sub)
          pacc[sub][nv] =
              __builtin_amdgcn_mfma_f32_16x16x32_bf16(ap[sub], bvv, pacc[sub][nv], 0, 0, 0);
      }
    }
    __syncthreads();
    cur ^= 1;
  }

  // at[b][q][g*64 + d]
#pragma unroll
  for (int sub = 0; sub < 2; ++sub)
#pragma unroll
    for (int nv = 0; nv < 4; ++nv)
#pragma unroll
      for (int i = 0; i < 4; ++i)
        at[bqk + ((long)(qr + sub * 16 + khi * 4 + i) << 10) + g * 64 + nv * 16 + fr] =
            f2bf(pacc[sub][nv][i]);
}

// one wave per 1024-elem row
__global__ __launch_bounds__(256) void layernorm_rows(const float* __restrict__ X,
                                                      const float* __restrict__ gamma,
                                                      const float* __restrict__ beta,
                                                      float* __restrict__ O) {
  const int row = blockIdx.x * 4 + (threadIdx.x >> 6);
  const int lane = threadIdx.x & 63;
  const float* x = X + (long)row * 1024 + lane * 4;
  f32x4 v[4];
  float s = 0.f, sq = 0.f;
#pragma unroll
  for (int j = 0; j < 4; ++j) {
    v[j] = *(const f32x4*)(x + j * 256);
#pragma unroll
    for (int e = 0; e < 4; ++e) {
      s += v[j][e];
      sq += v[j][e] * v[j][e];
    }
  }
#pragma unroll
  for (int off = 32; off; off >>= 1) {
    s += __shfl_xor(s, off);
    sq += __shfl_xor(sq, off);
  }
  const float mu = s * (1.f / 1024.f);
  const float var = sq * (1.f / 1024.f) - mu * mu;
  const float rstd = rsqrtf(var + 1e-5f);
  float* o = O + (long)row * 1024 + lane * 4;
#pragma unroll
  for (int j = 0; j < 4; ++j) {
    f32x4 g = *(const f32x4*)(gamma + lane * 4 + j * 256);
    f32x4 be = *(const f32x4*)(beta + lane * 4 + j * 256);
    f32x4 r;
#pragma unroll
    for (int e = 0; e < 4; ++e) r[e] = (v[j][e] - mu) * rstd * g[e] + be[e];
    *(f32x4*)(o + j * 256) = r;
  }
}

extern "C" void kernel_launch(void* const* d_in, const int* in_sizes, int n_in,
                              void* d_out, int out_size, void* d_ws, size_t ws_size,
                              hipStream_t stream) {
  const float* Q = (const float*)d_in[0];
  const float* KV = (const float*)d_in[1];
  const float* Wq = (const float*)d_in[2];
  const float* bq = (const float*)d_in[3];
  const float* Wk = (const float*)d_in[4];
  const float* bk = (const float*)d_in[5];
  const float* Wv = (const float*)d_in[6];
  const float* bv = (const float*)d_in[7];
  const float* Wp = (const float*)d_in[8];
  const float* bp = (const float*)d_in[9];
  const float* gamma = (const float*)d_in[10];
  const float* beta = (const float*)d_in[11];

  float* out = (float*)d_out;                       // [4M] f32
  float* scores = out + (long)4 * 1024 * 1024;      // [64M] f32

  char* ws = (char*)d_ws;
  short* Wqb = (short*)(ws);                        // 2MB each
  short* Wkb = (short*)(ws + (2L << 20));
  short* Wvb = (short*)(ws + (4L << 20));
  short* Wpb = (short*)(ws + (6L << 20));           // permuted columns
  short* qb  = (short*)(ws + (8L << 20));           // 8MB (pre-scaled by 1/8)
  short* kb  = (short*)(ws + (16L << 20));          // 8MB
  short* vt  = (short*)(ws + (24L << 20));          // 8MB
  short* at  = (short*)(ws + (32L << 20));          // 8MB, feat = g*64+d
  float* pre = (float*)(ws + (40L << 20));          // 16MB (written after attn)
  short* Qb  = (short*)(ws + (40L << 20));          // 8MB  (dead before pre)
  short* KVb = (short*)(ws + (48L << 20));          // 8MB  (dead before pre)
  float* bqs = (float*)(ws + (56L << 20));          // 4KB
  (void)ws_size; (void)in_sizes; (void)n_in; (void)out_size;

  // 1) all conversions, one launch
  prep<<<6660, 256, 0, stream>>>(Q, KV, Wq, Wk, Wv, Wp, bq,
                                 Qb, KVb, Wqb, Wkb, Wvb, Wpb, bqs);

  // 2) three projections, one launch
  proj_all<<<768, 256, 0, stream>>>(Qb, KVb, Wqb, Wkb, Wvb, bqs, bk, bv,
                                    qb, kb, vt);

  // 3) fused attention: scores (d_out) + at
  fused_attn<<<512, 256, 0, stream>>>(qb, kb, vt, scores, at);

  // 4) pre = at @ Wpb^T + bp + Q
  out_gemm<<<256, 256, 0, stream>>>(at, Wpb, bp, Q, pre);

  // 5) LayerNorm -> out
  layernorm_rows<<<1024, 256, 0, stream>>>(pre, gamma, beta, out);
}

// Round 11
// 164.876 us; speedup vs baseline: 2.3093x; 1.0653x over previous
//
#include <hip/hip_runtime.h>

typedef __attribute__((ext_vector_type(8))) short short8;
typedef __attribute__((ext_vector_type(4))) short s16x4;
typedef __attribute__((ext_vector_type(4))) float f32x4;
typedef __attribute__((ext_vector_type(2))) unsigned u32x2;

static __device__ __forceinline__ short f2bf(float x) {
  union { float f; unsigned u; } v; v.f = x;
  unsigned r = (v.u + 0x7fffu + ((v.u >> 16) & 1u)) >> 16;
  return (short)r;
}
// packed f32x2 -> bf16x2 (RNE), 1 VALU op
static __device__ __forceinline__ unsigned cvtpk(float lo, float hi) {
  unsigned r;
  asm("v_cvt_pk_bf16_f32 %0, %1, %2" : "=v"(r) : "v"(lo), "v"(hi));
  return r;
}

// async 16B global -> LDS (dest: wave-uniform base + lane*16; src: per-lane)
static __device__ __forceinline__ void gld16(const short* g, short* l) {
  __builtin_amdgcn_global_load_lds(
      (const __attribute__((address_space(1))) unsigned*)g,
      (__attribute__((address_space(3))) unsigned*)l, 16, 0, 0);
}

// ---------------- prep: all conversions in one launch ----------------
static __device__ __forceinline__ void conv8(const float* __restrict__ src,
                                             short* __restrict__ dst, int i,
                                             float scale) {
  const f32x4* s = (const f32x4*)(src + (long)i * 8);
  f32x4 a = s[0], b = s[1];
  short8 o;
  o[0] = f2bf(a[0] * scale); o[1] = f2bf(a[1] * scale);
  o[2] = f2bf(a[2] * scale); o[3] = f2bf(a[3] * scale);
  o[4] = f2bf(b[0] * scale); o[5] = f2bf(b[1] * scale);
  o[6] = f2bf(b[2] * scale); o[7] = f2bf(b[3] * scale);
  *(short8*)(dst + (long)i * 8) = o;
}

__global__ __launch_bounds__(256) void prep(
    const float* __restrict__ Q, const float* __restrict__ KV,
    const float* __restrict__ Wq, const float* __restrict__ Wk,
    const float* __restrict__ Wv, const float* __restrict__ Wp,
    const float* __restrict__ bq,
    short* __restrict__ Qb, short* __restrict__ KVb,
    short* __restrict__ Wqb, short* __restrict__ Wkb,
    short* __restrict__ Wvb, short* __restrict__ Wpb,
    float* __restrict__ bqs) {
  const int blk = blockIdx.x, tid = threadIdx.x;
  if (blk < 2048) {
    conv8(Q, Qb, blk * 256 + tid, 1.f);
  } else if (blk < 4096) {
    conv8(KV, KVb, (blk - 2048) * 256 + tid, 1.f);
  } else if (blk < 4608) {
    conv8(Wq, Wqb, (blk - 4096) * 256 + tid, 0.125f);   // fold 1/8 into Wq
  } else if (blk < 5120) {
    conv8(Wk, Wkb, (blk - 4608) * 256 + tid, 1.f);
  } else if (blk < 5632) {
    conv8(Wv, Wvb, (blk - 5120) * 256 + tid, 1.f);
  } else if (blk < 6656) {
    // Wpb[o][g*64+d] = Wp[o][d*16+g]
    __shared__ float row[1024];
    const long o = blk - 5632;
    *(f32x4*)&row[tid * 4] = *(const f32x4*)(Wp + o * 1024 + tid * 4);
    __syncthreads();
    const int f0 = tid * 4;
    s16x4 t;
#pragma unroll
    for (int j = 0; j < 4; ++j) {
      int f = f0 + j;
      t[j] = f2bf(row[((f & 63) << 4) + (f >> 6)]);
    }
    *(s16x4*)(Wpb + o * 1024 + f0) = t;
  } else {
    int i = (blk - 6656) * 256 + tid;
    bqs[i] = bq[i] * 0.125f;                            // fold 1/8 into bq
  }
}

// ---------------- 128x128 GEMM core (BK=64, dbuf, global_load_lds) ----------------
// Sm: 32768-short flat LDS. Buffers: A(buf)=Sm+buf*16384, B(buf)=Sm+buf*16384+8192.
// bf16 outputs go through an LDS-bounce (stride 136) for coalesced 16B stores.
// omode 0: C[row*1024+col]; omode 1 (vt): C[(b)<<20 | col<<10 | t].
template <typename OutT>
static __device__ __forceinline__ void gemm_core(
    const short* __restrict__ A, const short* __restrict__ B,
    OutT* __restrict__ C, const float* __restrict__ bias,
    const float* __restrict__ resid, int bm, int bn, int omode,
    short* Sm) {
  const int tid = threadIdx.x, lane = tid & 63, wave = tid >> 6;
  const int fr = lane & 15, khi = lane >> 4;
  const int wr = wave >> 1, wc = wave & 1;

  f32x4 acc[4][4];
#pragma unroll
  for (int m = 0; m < 4; ++m)
#pragma unroll
    for (int n = 0; n < 4; ++n) acc[m][n] = (f32x4){0.f, 0.f, 0.f, 0.f};

  auto stage = [&](int buf, int k0) {
    short* Asb = Sm + buf * 16384;
    short* Bsb = Asb + 8192;
#pragma unroll
    for (int it = 0; it < 4; ++it) {
      int l = it * 256 + tid;
      int r = l >> 3, c = (l & 7) ^ (r & 7);
      gld16(A + (long)(bm + r) * 1024 + k0 + c * 8, &Asb[l * 8]);
      gld16(B + (long)(bn + r) * 1024 + k0 + c * 8, &Bsb[l * 8]);
    }
  };

  stage(0, 0);
  __syncthreads();
  int cur = 0;
  for (int k0 = 0; k0 < 1024; k0 += 64) {
    if (k0 < 960) stage(cur ^ 1, k0 + 64);
    const short* Asb = Sm + cur * 16384;
    const short* Bsb = Asb + 8192;
#pragma unroll
    for (int ks = 0; ks < 64; ks += 32) {
      const int cc = (ks >> 3) + khi;
      short8 af[4], bf[4];
#pragma unroll
      for (int m = 0; m < 4; ++m) {
        const int ar = wr * 64 + m * 16 + fr;
        af[m] = *(const short8*)&Asb[ar * 64 + ((cc ^ (ar & 7)) * 8)];
      }
#pragma unroll
      for (int n = 0; n < 4; ++n) {
        const int br = wc * 64 + n * 16 + fr;
        bf[n] = *(const short8*)&Bsb[br * 64 + ((cc ^ (br & 7)) * 8)];
      }
#pragma unroll
      for (int m = 0; m < 4; ++m)
#pragma unroll
        for (int n = 0; n < 4; ++n)
          acc[m][n] = __builtin_amdgcn_mfma_f32_16x16x32_bf16(af[m], bf[n],
                                                              acc[m][n], 0, 0, 0);
    }
    __syncthreads();
    cur ^= 1;
  }

  const int col0 = fr, row0 = khi * 4;
  if constexpr (sizeof(OutT) == 2) {
    // bf16 output: LDS bounce -> coalesced 16B stores
#pragma unroll
    for (int m = 0; m < 4; ++m) {
#pragma unroll
      for (int n = 0; n < 4; ++n) {
        const int dgl = wc * 64 + n * 16 + col0;
        const float bi = bias[bn + dgl];
#pragma unroll
        for (int i = 0; i < 4; ++i) {
          const int tl = wr * 64 + m * 16 + row0 + i;
          const int a = (omode == 1) ? (dgl * 136 + tl) : (tl * 136 + dgl);
          Sm[a] = f2bf(acc[m][n][i] + bi);
        }
      }
    }
    __syncthreads();
    short* Cs = (short*)C;
#pragma unroll
    for (int it = 0; it < 8; ++it) {
      const int ch = it * 256 + tid;          // 2048 chunks of 16B
      const int r = ch >> 4, cchunk = ch & 15;
      short8 v8 = *(const short8*)&Sm[r * 136 + cchunk * 8];
      long addr;
      if (omode == 0)
        addr = (long)(bm + r) * 1024 + bn + cchunk * 8;
      else
        addr = ((long)(bm >> 10) << 20) + ((long)(bn + r) << 10) + (bm & 1023) +
               cchunk * 8;
      *(short8*)(Cs + addr) = v8;
    }
  } else {
    // f32 output (pre): scalar path, 64B segments
#pragma unroll
    for (int m = 0; m < 4; ++m) {
#pragma unroll
      for (int n = 0; n < 4; ++n) {
        const int gcol = bn + wc * 64 + n * 16 + col0;
        const float bi = bias[gcol];
#pragma unroll
        for (int i = 0; i < 4; ++i) {
          const int grow = bm + wr * 64 + m * 16 + row0 + i;
          float v = acc[m][n][i] + bi;
          if (resid) v += resid[(long)grow * 1024 + gcol];
          C[(long)grow * 1024 + gcol] = v;
        }
      }
    }
  }
}

// three projections in one launch: seg 0: qb, 1: kb, 2: vt
__global__ __launch_bounds__(256, 2) void proj_all(
    const short* __restrict__ Qb, const short* __restrict__ KVb,
    const short* __restrict__ Wqb, const short* __restrict__ Wkb,
    const short* __restrict__ Wvb,
    const float* __restrict__ bqs, const float* __restrict__ bk,
    const float* __restrict__ bv,
    short* __restrict__ qb, short* __restrict__ kb, short* __restrict__ vt) {
  __shared__ short Sm[32768];                // 64 KB
  int bid = blockIdx.x;
  int swz = (bid & 7) * 96 + (bid >> 3);     // 768 blocks, XCD-contiguous
  const int seg = swz >> 8, local = swz & 255;
  const int bm = (local >> 3) * 128, bn = (local & 7) * 128;
  if (seg == 0)
    gemm_core<short>(Qb, Wqb, qb, bqs, nullptr, bm, bn, 0, Sm);
  else if (seg == 1)
    gemm_core<short>(KVb, Wkb, kb, bk, nullptr, bm, bn, 0, Sm);
  else
    gemm_core<short>(KVb, Wvb, vt, bv, nullptr, bm, bn, 1, Sm);
}

// final GEMM: pre = at @ Wpb^T + bp + Q
__global__ __launch_bounds__(256, 2) void out_gemm(
    const short* __restrict__ at, const short* __restrict__ Wpb,
    const float* __restrict__ bp, const float* __restrict__ Q,
    float* __restrict__ pre) {
  __shared__ short Sm[32768];
  int bid = blockIdx.x;
  int swz = (bid & 7) * 32 + (bid >> 3);     // 256 blocks
  const int bm = (swz >> 3) * 128, bn = (swz & 7) * 128;
  gemm_core<float>(at, Wpb, pre, bp, Q, bm, bn, 0, Sm);
}

// ---------------- fused attention v11 ----------------
// 4 waves x 32 q-rows; K-feed permutation r2 = fr*4+nf (register-direct scores);
// at written via Ps LDS-bounce (coalesced 16B stores).
__global__ __launch_bounds__(256, 3) void fused_attn(
    const short* __restrict__ qb,   // [4][1024][1024] bf16, feat = g*64+d (x1/8)
    const short* __restrict__ kb,   // [4][1024][1024] bf16, feat = g*64+d
    const short* __restrict__ vt,   // [4][1024][1024] bf16, vt[b][d*16+g][t]
    float* __restrict__ scores,     // [64][1024][1024] f32
    short* __restrict__ at) {       // [4][1024][1024] bf16, feat = g*64+d
  constexpr int LP = 72;
  __shared__ short Ks[2][64 * 64];  // 16 KB  (XOR key = (row>>2)&7)
  __shared__ short Vs[2][64 * 64];  // 16 KB  (XOR key = row&7)
  __shared__ short Ps[128 * LP];    // 18 KB (wave-private 32-row slabs)

  int bid = blockIdx.x;
  bid = (bid & 7) * 64 + (bid >> 3);      // 8 z's per XCD
  const int z = bid >> 3, b = z >> 4, g = z & 15;
  const int q0 = (bid & 7) * 128;

  const int tid = threadIdx.x, lane = tid & 63, w = tid >> 6;
  const int fr = lane & 15, khi = lane >> 4;
  const long bqk = (long)b << 20;
  const int qr = q0 + w * 32;             // wave's first q row (32 rows)

  short8 aq[4];
#pragma unroll
  for (int sub = 0; sub < 2; ++sub) {
    const short* qrow = qb + bqk + (long)(qr + sub * 16 + fr) * 1024 + g * 64 + khi * 8;
    aq[sub * 2] = *(const short8*)qrow;
    aq[sub * 2 + 1] = *(const short8*)(qrow + 32);
  }
  const short* kgp = kb + bqk + g * 64;
  const short* vgp = vt + bqk;

  auto stageK = [&](int buf, int t0) {
#pragma unroll
    for (int it = 0; it < 2; ++it) {
      int l = it * 256 + tid;
      int r = l >> 3, c = (l & 7) ^ ((l >> 5) & 7);
      gld16(kgp + (long)(t0 + r) * 1024 + c * 8, &Ks[buf][l * 8]);
    }
  };
  auto stageV = [&](int buf, int t0) {
#pragma unroll
    for (int it = 0; it < 2; ++it) {
      int l = it * 256 + tid;
      int r = l >> 3, c = (l & 7) ^ (r & 7);
      gld16(vgp + ((long)(r * 16 + g) << 10) + t0 + c * 8, &Vs[buf][l * 8]);
    }
  };

  const int xk = fr & 7;                  // Ks read XOR key: (r2>>2)&7, r2=fr*4+nf

  // ---- pass 1: exp-sums ----
  float s4[2][4] = {{0.f, 0.f, 0.f, 0.f}, {0.f, 0.f, 0.f, 0.f}};
  stageK(0, 0);
  __syncthreads();
  int cur = 0;
  for (int t0 = 0; t0 < 1024; t0 += 64) {
    if (t0 < 960) stageK(cur ^ 1, t0 + 64);
    f32x4 sacc[2][4];
#pragma unroll
    for (int sub = 0; sub < 2; ++sub)
#pragma unroll
      for (int nf = 0; nf < 4; ++nf) sacc[sub][nf] = (f32x4){0.f, 0.f, 0.f, 0.f};
#pragma unroll
    for (int nf = 0; nf < 4; ++nf) {
      const int r2 = fr * 4 + nf;
      short8 b0 = *(const short8*)&Ks[cur][r2 * 64 + ((khi ^ xk) * 8)];
      short8 b1 = *(const short8*)&Ks[cur][r2 * 64 + (((khi + 4) ^ xk) * 8)];
#pragma unroll
      for (int sub = 0; sub < 2; ++sub) {
        sacc[sub][nf] =
            __builtin_amdgcn_mfma_f32_16x16x32_bf16(aq[sub * 2], b0, sacc[sub][nf], 0, 0, 0);
        sacc[sub][nf] =
            __builtin_amdgcn_mfma_f32_16x16x32_bf16(aq[sub * 2 + 1], b1, sacc[sub][nf], 0, 0, 0);
      }
    }
#pragma unroll
    for (int sub = 0; sub < 2; ++sub)
#pragma unroll
      for (int nf = 0; nf < 4; ++nf)
#pragma unroll
        for (int i = 0; i < 4; ++i) s4[sub][i] += __expf(sacc[sub][nf][i]);
    __syncthreads();
    cur ^= 1;
  }
  float inv4[2][4];
#pragma unroll
  for (int sub = 0; sub < 2; ++sub)
#pragma unroll
    for (int i = 0; i < 4; ++i) {
      float s = s4[sub][i];
      s += __shfl_xor(s, 1);
      s += __shfl_xor(s, 2);
      s += __shfl_xor(s, 4);
      s += __shfl_xor(s, 8);
      inv4[sub][i] = 1.f / s;
    }

  // ---- pass 2: recompute, direct score store, packed Ps, PV ----
  f32x4 pacc[2][4];
#pragma unroll
  for (int sub = 0; sub < 2; ++sub)
#pragma unroll
    for (int nv = 0; nv < 4; ++nv) pacc[sub][nv] = (f32x4){0.f, 0.f, 0.f, 0.f};

  stageK(0, 0);
  stageV(0, 0);
  __syncthreads();
  cur = 0;
  for (int t0 = 0; t0 < 1024; t0 += 64) {
    if (t0 < 960) {
      stageK(cur ^ 1, t0 + 64);
      stageV(cur ^ 1, t0 + 64);
    }
    f32x4 sacc[2][4];
#pragma unroll
    for (int sub = 0; sub < 2; ++sub)
#pragma unroll
      for (int nf = 0; nf < 4; ++nf) sacc[sub][nf] = (f32x4){0.f, 0.f, 0.f, 0.f};
#pragma unroll
    for (int nf = 0; nf < 4; ++nf) {
      const int r2 = fr * 4 + nf;
      short8 b0 = *(const short8*)&Ks[cur][r2 * 64 + ((khi ^ xk) * 8)];
      short8 b1 = *(const short8*)&Ks[cur][r2 * 64 + (((khi + 4) ^ xk) * 8)];
#pragma unroll
      for (int sub = 0; sub < 2; ++sub) {
        sacc[sub][nf] =
            __builtin_amdgcn_mfma_f32_16x16x32_bf16(aq[sub * 2], b0, sacc[sub][nf], 0, 0, 0);
        sacc[sub][nf] =
            __builtin_amdgcn_mfma_f32_16x16x32_bf16(aq[sub * 2 + 1], b1, sacc[sub][nf], 0, 0, 0);
      }
    }
    // epilogue: lane holds keys fr*4+{0..3} for rows khi*4+i (+sub*16)
#pragma unroll
    for (int sub = 0; sub < 2; ++sub) {
#pragma unroll
      for (int i = 0; i < 4; ++i) {
        f32x4 o;
#pragma unroll
        for (int nf = 0; nf < 4; ++nf)
          o[nf] = __expf(sacc[sub][nf][i]) * inv4[sub][i];
        const int row = sub * 16 + khi * 4 + i;
        __builtin_nontemporal_store(
            o, (f32x4*)&scores[((long)z << 20) + ((long)(qr + row) << 10) + t0 + fr * 4]);
        u32x2 pp;
        pp[0] = cvtpk(o[0], o[1]);
        pp[1] = cvtpk(o[2], o[3]);
        *(u32x2*)&Ps[(w * 32 + row) * LP + fr * 4] = pp;
      }
    }

    // PV: V fragments shared across the two sub-tiles
#pragma unroll
    for (int ks = 0; ks < 64; ks += 32) {
      const int cc = (ks >> 3) + khi;
      short8 ap[2];
#pragma unroll
      for (int sub = 0; sub < 2; ++sub)
        ap[sub] = *(const short8*)&Ps[(w * 32 + sub * 16 + fr) * LP + ks + khi * 8];
#pragma unroll
      for (int nv = 0; nv < 4; ++nv) {
        const int dr = nv * 16 + fr;
        short8 bvv = *(const short8*)&Vs[cur][dr * 64 + ((cc ^ (dr & 7)) * 8)];
#pragma unroll
        for (int sub = 0; sub < 2; ++sub)
          pacc[sub][nv] =
              __builtin_amdgcn_mfma_f32_16x16x32_bf16(ap[sub], bvv, pacc[sub][nv], 0, 0, 0);
      }
    }
    __syncthreads();
    cur ^= 1;
  }

  // at bounce via Ps (wave-private slab, no barrier needed)
#pragma unroll
  for (int sub = 0; sub < 2; ++sub)
#pragma unroll
    for (int nv = 0; nv < 4; ++nv)
#pragma unroll
      for (int i = 0; i < 4; ++i)
        Ps[(w * 32 + sub * 16 + khi * 4 + i) * LP + nv * 16 + fr] =
            f2bf(pacc[sub][nv][i]);
  const long atbase = bqk + ((long)qr << 10) + g * 64;
#pragma unroll
  for (int it = 0; it < 4; ++it) {
    const int ch = it * 64 + lane;          // 256 chunks: 32 rows x 8 chunks
    const int row = ch >> 3, fc = ch & 7;
    s16x4 lo = *(const s16x4*)&Ps[(w * 32 + row) * LP + fc * 8];
    s16x4 hi = *(const s16x4*)&Ps[(w * 32 + row) * LP + fc * 8 + 4];
    short8 v8;
    v8[0] = lo[0]; v8[1] = lo[1]; v8[2] = lo[2]; v8[3] = lo[3];
    v8[4] = hi[0]; v8[5] = hi[1]; v8[6] = hi[2]; v8[7] = hi[3];
    *(short8*)(at + atbase + ((long)row << 10) + fc * 8) = v8;
  }
}

// one wave per 1024-elem row
__global__ __launch_bounds__(256) void layernorm_rows(const float* __restrict__ X,
                                                      const float* __restrict__ gamma,
                                                      const float* __restrict__ beta,
                                                      float* __restrict__ O) {
  const int row = blockIdx.x * 4 + (threadIdx.x >> 6);
  const int lane = threadIdx.x & 63;
  const float* x = X + (long)row * 1024 + lane * 4;
  f32x4 v[4];
  float s = 0.f, sq = 0.f;
#pragma unroll
  for (int j = 0; j < 4; ++j) {
    v[j] = *(const f32x4*)(x + j * 256);
#pragma unroll
    for (int e = 0; e < 4; ++e) {
      s += v[j][e];
      sq += v[j][e] * v[j][e];
    }
  }
#pragma unroll
  for (int off = 32; off; off >>= 1) {
    s += __shfl_xor(s, off);
    sq += __shfl_xor(sq, off);
  }
  const float mu = s * (1.f / 1024.f);
  const float var = sq * (1.f / 1024.f) - mu * mu;
  const float rstd = rsqrtf(var + 1e-5f);
  float* o = O + (long)row * 1024 + lane * 4;
#pragma unroll
  for (int j = 0; j < 4; ++j) {
    f32x4 g = *(const f32x4*)(gamma + lane * 4 + j * 256);
    f32x4 be = *(const f32x4*)(beta + lane * 4 + j * 256);
    f32x4 r;
#pragma unroll
    for (int e = 0; e < 4; ++e) r[e] = (v[j][e] - mu) * rstd * g[e] + be[e];
    *(f32x4*)(o + j * 256) = r;
  }
}

extern "C" void kernel_launch(void* const* d_in, const int* in_sizes, int n_in,
                              void* d_out, int out_size, void* d_ws, size_t ws_size,
                              hipStream_t stream) {
  const float* Q = (const float*)d_in[0];
  const float* KV = (const float*)d_in[1];
  const float* Wq = (const float*)d_in[2];
  const float* bq = (const float*)d_in[3];
  const float* Wk = (const float*)d_in[4];
  const float* bk = (const float*)d_in[5];
  const float* Wv = (const float*)d_in[6];
  const float* bv = (const float*)d_in[7];
  const float* Wp = (const float*)d_in[8];
  const float* bp = (const float*)d_in[9];
  const float* gamma = (const float*)d_in[10];
  const float* beta = (const float*)d_in[11];

  float* out = (float*)d_out;                       // [4M] f32
  float* scores = out + (long)4 * 1024 * 1024;      // [64M] f32

  char* ws = (char*)d_ws;
  short* Wqb = (short*)(ws);                        // 2MB each
  short* Wkb = (short*)(ws + (2L << 20));
  short* Wvb = (short*)(ws + (4L << 20));
  short* Wpb = (short*)(ws + (6L << 20));           // permuted columns
  short* qb  = (short*)(ws + (8L << 20));           // 8MB (pre-scaled by 1/8)
  short* kb  = (short*)(ws + (16L << 20));          // 8MB
  short* vt  = (short*)(ws + (24L << 20));          // 8MB
  short* at  = (short*)(ws + (32L << 20));          // 8MB, feat = g*64+d
  float* pre = (float*)(ws + (40L << 20));          // 16MB (written after attn)
  short* Qb  = (short*)(ws + (40L << 20));          // 8MB  (dead before pre)
  short* KVb = (short*)(ws + (48L << 20));          // 8MB  (dead before pre)
  float* bqs = (float*)(ws + (56L << 20));          // 4KB
  (void)ws_size; (void)in_sizes; (void)n_in; (void)out_size;

  // 1) all conversions, one launch
  prep<<<6660, 256, 0, stream>>>(Q, KV, Wq, Wk, Wv, Wp, bq,
                                 Qb, KVb, Wqb, Wkb, Wvb, Wpb, bqs);

  // 2) three projections, one launch
  proj_all<<<768, 256, 0, stream>>>(Qb, KVb, Wqb, Wkb, Wvb, bqs, bk, bv,
                                    qb, kb, vt);

  // 3) fused attention: scores (d_out) + at
  fused_attn<<<512, 256, 0, stream>>>(qb, kb, vt, scores, at);

  // 4) pre = at @ Wpb^T + bp + Q
  out_gemm<<<256, 256, 0, stream>>>(at, Wpb, bp, Q, pre);

  // 5) LayerNorm -> out
  layernorm_rows<<<1024, 256, 0, stream>>>(pre, gamma, beta, out);
}